// Round 4
// baseline (435.321 us; speedup 1.0000x reference)
//
#include <hip/hip_runtime.h>

#define D 128
#define BSHIFT 6   // 64 nodes per bucket for the binned edge sort

typedef __attribute__((ext_vector_type(8))) short short8;
typedef __attribute__((ext_vector_type(4))) float f32x4;

__device__ __forceinline__ unsigned short f2b(float f) {
    unsigned u = __builtin_bit_cast(unsigned, f);
    u += 0x7fffu + ((u >> 16) & 1u);           // round-to-nearest-even
    return (unsigned short)(u >> 16);
}
__device__ __forceinline__ float b2f(unsigned short b) {
    unsigned u = ((unsigned)b) << 16;
    return __builtin_bit_cast(float, u);
}

// ---------------- CSR build ----------------

__global__ void count_kernel(const int* __restrict__ dst, int* __restrict__ counts, int E) {
    int e = blockIdx.x * blockDim.x + threadIdx.x;
    if (e < E) atomicAdd(&counts[dst[e]], 1);
}

__global__ void scan_part_kernel(const int* __restrict__ counts, int* __restrict__ partials, int n) {
    __shared__ int lds[256];
    int t = threadIdx.x;
    int base = blockIdx.x * 1024 + t * 4;
    int s = 0;
    if (base + 3 < n) {
        int4 v = *reinterpret_cast<const int4*>(counts + base);
        s = v.x + v.y + v.z + v.w;
    } else {
        for (int i = 0; i < 4; ++i) if (base + i < n) s += counts[base + i];
    }
    lds[t] = s;
    __syncthreads();
    for (int d = 128; d > 0; d >>= 1) { if (t < d) lds[t] += lds[t + d]; __syncthreads(); }
    if (t == 0) partials[blockIdx.x] = lds[0];
}

__global__ void scan_base_kernel(int* __restrict__ partials, int nb, int* __restrict__ offsets, int n) {
    __shared__ int lds[256];
    int t = threadIdx.x;
    int v = (t < nb) ? partials[t] : 0;
    lds[t] = v;
    __syncthreads();
    for (int d = 1; d < 256; d <<= 1) {
        int u = (t >= d) ? lds[t - d] : 0;
        __syncthreads();
        lds[t] += u;
        __syncthreads();
    }
    if (t < nb) partials[t] = lds[t] - v;
    if (t == 255) offsets[n] = lds[255];
}

__global__ void scan_write_kernel(const int* __restrict__ counts, const int* __restrict__ partials,
                                  int* __restrict__ offsets, int n) {
    __shared__ int lds[256];
    int t = threadIdx.x;
    int base = blockIdx.x * 1024 + t * 4;
    int v[4];
    for (int i = 0; i < 4; ++i) v[i] = (base + i < n) ? counts[base + i] : 0;
    int s = v[0] + v[1] + v[2] + v[3];
    lds[t] = s;
    __syncthreads();
    for (int d = 1; d < 256; d <<= 1) {
        int u = (t >= d) ? lds[t - d] : 0;
        __syncthreads();
        lds[t] += u;
        __syncthreads();
    }
    int run = (t == 0 ? 0 : lds[t - 1]) + partials[blockIdx.x];
    for (int i = 0; i < 4; ++i) {
        if (base + i < n) offsets[base + i] = run;
        run += v[i];
    }
}

// Pass A: bin edges by dst>>BSHIFT into staging (bucket base = offsets[b<<BSHIFT]).
// Writes within a bucket are cursor-sequential -> dense line utilization.
__global__ void binA_kernel(const int* __restrict__ src, const int* __restrict__ dst,
                            const int* __restrict__ offsets, int* __restrict__ cursorA,
                            int2* __restrict__ staging, int E) {
    int e = blockIdx.x * blockDim.x + threadIdx.x;
    if (e < E) {
        int d = dst[e];
        int b = d >> BSHIFT;
        int p = atomicAdd(&cursorA[b], 1);
        staging[offsets[b << BSHIFT] + p] = make_int2(src[e], d);
    }
}

// Pass B: staging is bucket-grouped; csr scatter now lands in a ~4-8 KB window (cache-hit).
__global__ void binB_kernel(const int2* __restrict__ staging, const int* __restrict__ offsets,
                            int* __restrict__ cursor, int* __restrict__ csr, int E) {
    int e = blockIdx.x * blockDim.x + threadIdx.x;
    if (e < E) {
        int2 sd = staging[e];
        int p = atomicAdd(&cursor[sd.y], 1);
        csr[offsets[sd.y] + p] = sd.x;
    }
}

// ---------------- bf16 prep ----------------

__global__ void cast_x_kernel(const float* __restrict__ x, unsigned short* __restrict__ acat, int n16) {
    int g = blockIdx.x * blockDim.x + threadIdx.x;   // one 8-elem chunk
    if (g >= n16) return;
    int row = g >> 4, chunk = g & 15;
    const float4 v0 = *reinterpret_cast<const float4*>(x + (size_t)g * 8);
    const float4 v1 = *reinterpret_cast<const float4*>(x + (size_t)g * 8 + 4);
    short8 r;
    r[0] = (short)f2b(v0.x); r[1] = (short)f2b(v0.y); r[2] = (short)f2b(v0.z); r[3] = (short)f2b(v0.w);
    r[4] = (short)f2b(v1.x); r[5] = (short)f2b(v1.y); r[6] = (short)f2b(v1.z); r[7] = (short)f2b(v1.w);
    *reinterpret_cast<short8*>(acat + (size_t)row * 256 + 128 + chunk * 8) = r;
}

__global__ void prep_w_kernel(const float* __restrict__ W1l, const float* __restrict__ W1r,
                              const float* __restrict__ W2l, const float* __restrict__ W2r,
                              unsigned short* __restrict__ WT1, unsigned short* __restrict__ WT2) {
    int layer = blockIdx.x >> 7;
    int j = blockIdx.x & 127;
    int k = threadIdx.x;  // 0..255
    const float* Wl = layer ? W2l : W1l;
    const float* Wr = layer ? W2r : W1r;
    unsigned short* WT = layer ? WT2 : WT1;
    float v = (k < 128) ? Wl[k * D + j] : Wr[(k - 128) * D + j];
    WT[(size_t)j * 256 + k] = f2b(v);
}

// ---------------- mean aggregation (bf16 gather, f32 accumulate) ----------------

__global__ void aggregate_kernel(const unsigned short* __restrict__ xin,   // row stride 256 (pre-offset +128)
                                 const int* __restrict__ offsets, const int* __restrict__ csr,
                                 unsigned short* __restrict__ out,         // row stride 256 (offset 0)
                                 int nnodes) {
    int node = blockIdx.x * 16 + (threadIdx.x >> 4);
    int l16 = threadIdx.x & 15;
    if (node >= nnodes) return;
    int lo = offsets[node], hi = offsets[node + 1];
    float acc[8] = {0.f, 0.f, 0.f, 0.f, 0.f, 0.f, 0.f, 0.f};
    for (int k = lo; k < hi; ++k) {
        int s = csr[k];
        const short8 v = *reinterpret_cast<const short8*>(xin + (size_t)s * 256 + l16 * 8);
        for (int i = 0; i < 8; ++i) acc[i] += b2f((unsigned short)v[i]);
    }
    float inv = 1.0f / fmaxf((float)(hi - lo), 1.0f);
    short8 r;
    for (int i = 0; i < 8; ++i) r[i] = (short)f2b(acc[i] * inv);
    *reinterpret_cast<short8*>(out + (size_t)node * 256 + l16 * 8) = r;
}

// ---------------- fused SAGE linear via MFMA ----------------
// out[n][0..127] = l2norm(Acat[n][0..255] @ Wcat + b), opt ReLU; K=256.

template <bool RELU>
__global__ __launch_bounds__(256) void sage_mfma_kernel(
    const unsigned short* __restrict__ Acat, const unsigned short* __restrict__ WT,
    const float* __restrict__ bias, unsigned short* __restrict__ out,
    int out_stride, int nnodes) {

    const int tid = threadIdx.x;
    const int w = tid >> 6, l = tid & 63;
    const int r16 = l & 15, g = l >> 4;
    const int rowbase = blockIdx.x * 64 + w * 16;

    f32x4 acc[8];
#pragma unroll
    for (int j = 0; j < 8; ++j) {
        float bj = bias[j * 16 + r16];
        acc[j] = (f32x4){bj, bj, bj, bj};
    }

    const unsigned short* ap = Acat + (size_t)(rowbase + r16) * 256 + g * 8;
    const unsigned short* bp = WT + (size_t)r16 * 256 + g * 8;

#pragma unroll
    for (int ks = 0; ks < 8; ++ks) {
        const short8 a = *reinterpret_cast<const short8*>(ap + ks * 32);
#pragma unroll
        for (int j = 0; j < 8; ++j) {
            const short8 b = *reinterpret_cast<const short8*>(bp + j * 4096 + ks * 32);
            acc[j] = __builtin_amdgcn_mfma_f32_16x16x32_bf16(a, b, acc[j], 0, 0, 0);
        }
    }

    float ss[4] = {0.f, 0.f, 0.f, 0.f};
#pragma unroll
    for (int j = 0; j < 8; ++j)
#pragma unroll
        for (int i = 0; i < 4; ++i) ss[i] += acc[j][i] * acc[j][i];
#pragma unroll
    for (int m = 1; m < 16; m <<= 1)
#pragma unroll
        for (int i = 0; i < 4; ++i) ss[i] += __shfl_xor(ss[i], m, 64);

#pragma unroll
    for (int i = 0; i < 4; ++i) {
        int row = rowbase + g * 4 + i;
        if (row >= nnodes) continue;
        float sc = 1.0f / fmaxf(sqrtf(ss[i]), 1e-12f);
#pragma unroll
        for (int j = 0; j < 8; ++j) {
            float v = acc[j][i] * sc;
            if (RELU) v = fmaxf(v, 0.f);
            out[(size_t)row * out_stride + j * 16 + r16] = f2b(v);
        }
    }
}

// ---------------- head: logits = h@Wfc + bfc, softmax over 2 classes ----------------

__global__ void head_kernel(const unsigned short* __restrict__ h, const float* __restrict__ Wfc,
                            const float* __restrict__ bfc, float* __restrict__ out, int nnodes) {
    int wid  = (blockIdx.x * blockDim.x + threadIdx.x) >> 6;
    int lane = threadIdx.x & 63;
    if (wid >= nnodes) return;
    float v0 = b2f(h[(size_t)wid * D + lane]);
    float v1 = b2f(h[(size_t)wid * D + 64 + lane]);
    float d0 = v0 * Wfc[lane * 2]       + v1 * Wfc[(lane + 64) * 2];
    float d1 = v0 * Wfc[lane * 2 + 1]   + v1 * Wfc[(lane + 64) * 2 + 1];
    for (int m = 1; m < 64; m <<= 1) {
        d0 += __shfl_xor(d0, m, 64);
        d1 += __shfl_xor(d1, m, 64);
    }
    if (lane == 0) {
        d0 += bfc[0]; d1 += bfc[1];
        float mx = fmaxf(d0, d1);
        float e0 = expf(d0 - mx), e1 = expf(d1 - mx);
        float inv = 1.0f / (e0 + e1);
        out[(size_t)wid * 2]     = e0 * inv;
        out[(size_t)wid * 2 + 1] = e1 * inv;
    }
}

// ---------------- launch ----------------

extern "C" void kernel_launch(void* const* d_in, const int* in_sizes, int n_in,
                              void* d_out, int out_size, void* d_ws, size_t ws_size,
                              hipStream_t stream) {
    const float* x   = (const float*)d_in[0];
    const int*   ei  = (const int*)d_in[1];
    const float* W1l = (const float*)d_in[2];
    const float* b1l = (const float*)d_in[3];
    const float* W1r = (const float*)d_in[4];
    const float* W2l = (const float*)d_in[5];
    const float* b2l = (const float*)d_in[6];
    const float* W2r = (const float*)d_in[7];
    const float* Wfc = (const float*)d_in[8];
    const float* bfc = (const float*)d_in[9];

    const int N = in_sizes[0] / D;
    const int E = in_sizes[1] / 2;
    const int* src = ei;        // edge_index[0]
    const int* dst = ei + E;    // edge_index[1]
    const int NB = (N + (1 << BSHIFT) - 1) >> BSHIFT;   // buckets

    // workspace: bf16 feature tables first (16B aligned), ints after
    unsigned short* Acat1 = (unsigned short*)d_ws;        // N x 256 : [agg1 | xb]
    unsigned short* Acat2 = Acat1 + (size_t)N * 256;      // N x 256 : [agg2 | h1]
    unsigned short* h2    = Acat1;                        // N x 128 (reuses Acat1; gemm2 reads only Acat2)
    int2* staging         = (int2*)Acat2;                 // E x int2 (dead until mfma1, aliasing safe)
    unsigned short* WT1   = Acat2 + (size_t)N * 256;      // 128 x 256
    unsigned short* WT2   = WT1 + 128 * 256;              // 128 x 256
    int* counts  = (int*)(WT2 + 128 * 256);               // N
    int* offsets = counts + N;                            // N+1
    int* cursor  = offsets + N + 1;                       // N
    int* cursorA = cursor + N;                            // NB
    int* csr     = cursorA + NB;                          // E
    int* partials = csr + E;                              // <=256

    const int nb_scan = (N + 1023) / 1024;

    hipMemsetAsync(counts, 0, (size_t)(3 * N + 1 + NB) * sizeof(int), stream);

    // CSR build (count -> scan -> two-pass binned fill)
    count_kernel<<<(E + 255) / 256, 256, 0, stream>>>(dst, counts, E);
    scan_part_kernel<<<nb_scan, 256, 0, stream>>>(counts, partials, N);
    scan_base_kernel<<<1, 256, 0, stream>>>(partials, nb_scan, offsets, N);
    scan_write_kernel<<<nb_scan, 256, 0, stream>>>(counts, partials, offsets, N);
    binA_kernel<<<(E + 255) / 256, 256, 0, stream>>>(src, dst, offsets, cursorA, staging, E);
    binB_kernel<<<(E + 255) / 256, 256, 0, stream>>>(staging, offsets, cursor, csr, E);

    // bf16 prep
    cast_x_kernel<<<(N * 16 + 255) / 256, 256, 0, stream>>>(x, Acat1, N * 16);
    prep_w_kernel<<<256, 256, 0, stream>>>(W1l, W1r, W2l, W2r, WT1, WT2);

    // layer 1: agg(xb) -> Acat1[:,0:128]; h1 = l2norm(Acat1@Wcat1+b) -> Acat2[:,128:256]
    aggregate_kernel<<<(N + 15) / 16, 256, 0, stream>>>(Acat1 + 128, offsets, csr, Acat1, N);
    sage_mfma_kernel<true><<<(N + 63) / 64, 256, 0, stream>>>(Acat1, WT1, b1l, Acat2 + 128, 256, N);

    // layer 2: agg(h1) -> Acat2[:,0:128]; h2 = l2norm(Acat2@Wcat2+b) -> h2 (stride 128)
    aggregate_kernel<<<(N + 15) / 16, 256, 0, stream>>>(Acat2 + 128, offsets, csr, Acat2, N);
    sage_mfma_kernel<false><<<(N + 63) / 64, 256, 0, stream>>>(Acat2, WT2, b2l, h2, D, N);

    // head + softmax
    head_kernel<<<(N + 3) / 4, 256, 0, stream>>>(h2, Wfc, bfc, (float*)d_out, N);
}

// Round 5
// 263.596 us; speedup vs baseline: 1.6515x; 1.6515x over previous
//
#include <hip/hip_runtime.h>

#define D 128
#define CBITS 10   // 1024 nodes per coarse bucket (<=64 buckets for N<=65536)

typedef __attribute__((ext_vector_type(8))) short short8;
typedef __attribute__((ext_vector_type(4))) float f32x4;

__device__ __forceinline__ unsigned short f2b(float f) {
    unsigned u = __builtin_bit_cast(unsigned, f);
    u += 0x7fffu + ((u >> 16) & 1u);           // round-to-nearest-even
    return (unsigned short)(u >> 16);
}
__device__ __forceinline__ float b2f(unsigned short b) {
    unsigned u = ((unsigned)b) << 16;
    return __builtin_bit_cast(float, u);
}

// ---------------- CSR build ----------------

__global__ void count_kernel(const int* __restrict__ dst, int* __restrict__ counts, int E) {
    int e = blockIdx.x * blockDim.x + threadIdx.x;
    if (e < E) atomicAdd(&counts[dst[e]], 1);
}

__global__ void scan_part_kernel(const int* __restrict__ counts, int* __restrict__ partials, int n) {
    __shared__ int lds[256];
    int t = threadIdx.x;
    int base = blockIdx.x * 1024 + t * 4;
    int s = 0;
    if (base + 3 < n) {
        int4 v = *reinterpret_cast<const int4*>(counts + base);
        s = v.x + v.y + v.z + v.w;
    } else {
        for (int i = 0; i < 4; ++i) if (base + i < n) s += counts[base + i];
    }
    lds[t] = s;
    __syncthreads();
    for (int d = 128; d > 0; d >>= 1) { if (t < d) lds[t] += lds[t + d]; __syncthreads(); }
    if (t == 0) partials[blockIdx.x] = lds[0];
}

__global__ void scan_base_kernel(int* __restrict__ partials, int nb, int* __restrict__ offsets, int n) {
    __shared__ int lds[256];
    int t = threadIdx.x;
    int v = (t < nb) ? partials[t] : 0;
    lds[t] = v;
    __syncthreads();
    for (int d = 1; d < 256; d <<= 1) {
        int u = (t >= d) ? lds[t - d] : 0;
        __syncthreads();
        lds[t] += u;
        __syncthreads();
    }
    if (t < nb) partials[t] = lds[t] - v;
    if (t == 255) offsets[n] = lds[255];
}

__global__ void scan_write_kernel(const int* __restrict__ counts, const int* __restrict__ partials,
                                  int* __restrict__ offsets, int n) {
    __shared__ int lds[256];
    int t = threadIdx.x;
    int base = blockIdx.x * 1024 + t * 4;
    int v[4];
    for (int i = 0; i < 4; ++i) v[i] = (base + i < n) ? counts[base + i] : 0;
    int s = v[0] + v[1] + v[2] + v[3];
    lds[t] = s;
    __syncthreads();
    for (int d = 1; d < 256; d <<= 1) {
        int u = (t >= d) ? lds[t - d] : 0;
        __syncthreads();
        lds[t] += u;
        __syncthreads();
    }
    int run = (t == 0 ? 0 : lds[t - 1]) + partials[blockIdx.x];
    for (int i = 0; i < 4; ++i) {
        if (base + i < n) offsets[base + i] = run;
        run += v[i];
    }
}

// Pass 1: coarse bucket sort with PER-BLOCK LDS histograms.
// One global atomic per (block,bucket) instead of per edge (R4's binA lesson:
// 800K atomics on 782 counters serialized at ~1023 bumps/line -> 190us).
__global__ __launch_bounds__(256) void bin_coarse_kernel(
    const int* __restrict__ src, const int* __restrict__ dst,
    const int* __restrict__ offsets, int* __restrict__ cursorA,
    int2* __restrict__ staging, int E) {

    __shared__ int hist[64];
    __shared__ int lcur[64];
    const int t = threadIdx.x;
    if (t < 64) hist[t] = 0;
    __syncthreads();

    const int base = blockIdx.x * 4096;
    int sreg[16], dreg[16];
#pragma unroll
    for (int i = 0; i < 16; ++i) {
        int e = base + i * 256 + t;
        int s = 0, d = -1;
        if (e < E) {
            s = src[e]; d = dst[e];
            atomicAdd(&hist[d >> CBITS], 1);
        }
        sreg[i] = s; dreg[i] = d;
    }
    __syncthreads();
    if (t < 64) {
        int h = hist[t];
        lcur[t] = h ? atomicAdd(&cursorA[t], h) : 0;   // absolute base within bucket
    }
    __syncthreads();
#pragma unroll
    for (int i = 0; i < 16; ++i) {
        if (dreg[i] >= 0) {
            int b = dreg[i] >> CBITS;
            int p = atomicAdd(&lcur[b], 1);            // LDS atomic: cheap
            staging[offsets[b << CBITS] + p] = make_int2(sreg[i], dreg[i]);
        }
    }
}

// Pass 2: staging is bucket-grouped; csr scatter lands in a ~64KB window (L2-hit).
__global__ void bin_fine_kernel(const int2* __restrict__ staging, const int* __restrict__ offsets,
                                int* __restrict__ cursor, int* __restrict__ csr, int E) {
    int e = blockIdx.x * blockDim.x + threadIdx.x;
    if (e < E) {
        int2 sd = staging[e];
        int p = atomicAdd(&cursor[sd.y], 1);
        csr[offsets[sd.y] + p] = sd.x;
    }
}

// ---------------- bf16 prep ----------------

__global__ void cast_x_kernel(const float* __restrict__ x, unsigned short* __restrict__ acat, int n16) {
    int g = blockIdx.x * blockDim.x + threadIdx.x;   // one 8-elem chunk
    if (g >= n16) return;
    int row = g >> 4, chunk = g & 15;
    const float4 v0 = *reinterpret_cast<const float4*>(x + (size_t)g * 8);
    const float4 v1 = *reinterpret_cast<const float4*>(x + (size_t)g * 8 + 4);
    short8 r;
    r[0] = (short)f2b(v0.x); r[1] = (short)f2b(v0.y); r[2] = (short)f2b(v0.z); r[3] = (short)f2b(v0.w);
    r[4] = (short)f2b(v1.x); r[5] = (short)f2b(v1.y); r[6] = (short)f2b(v1.z); r[7] = (short)f2b(v1.w);
    *reinterpret_cast<short8*>(acat + (size_t)row * 256 + 128 + chunk * 8) = r;
}

__global__ void prep_w_kernel(const float* __restrict__ W1l, const float* __restrict__ W1r,
                              const float* __restrict__ W2l, const float* __restrict__ W2r,
                              unsigned short* __restrict__ WT1, unsigned short* __restrict__ WT2) {
    int layer = blockIdx.x >> 7;
    int j = blockIdx.x & 127;
    int k = threadIdx.x;  // 0..255
    const float* Wl = layer ? W2l : W1l;
    const float* Wr = layer ? W2r : W1r;
    unsigned short* WT = layer ? WT2 : WT1;
    float v = (k < 128) ? Wl[k * D + j] : Wr[(k - 128) * D + j];
    WT[(size_t)j * 256 + k] = f2b(v);
}

// ---------------- mean aggregation (bf16 gather, f32 accumulate) ----------------

__global__ void aggregate_kernel(const unsigned short* __restrict__ xin,   // row stride 256 (pre-offset +128)
                                 const int* __restrict__ offsets, const int* __restrict__ csr,
                                 unsigned short* __restrict__ out,         // row stride 256 (offset 0)
                                 int nnodes) {
    int node = blockIdx.x * 16 + (threadIdx.x >> 4);
    int l16 = threadIdx.x & 15;
    if (node >= nnodes) return;
    int lo = offsets[node], hi = offsets[node + 1];
    float acc[8] = {0.f, 0.f, 0.f, 0.f, 0.f, 0.f, 0.f, 0.f};
    for (int k = lo; k < hi; ++k) {
        int s = csr[k];
        const short8 v = *reinterpret_cast<const short8*>(xin + (size_t)s * 256 + l16 * 8);
        for (int i = 0; i < 8; ++i) acc[i] += b2f((unsigned short)v[i]);
    }
    float inv = 1.0f / fmaxf((float)(hi - lo), 1.0f);
    short8 r;
    for (int i = 0; i < 8; ++i) r[i] = (short)f2b(acc[i] * inv);
    *reinterpret_cast<short8*>(out + (size_t)node * 256 + l16 * 8) = r;
}

// ---------------- fused SAGE linear via MFMA ----------------
// out[n][0..127] = l2norm(Acat[n][0..255] @ Wcat + b), opt ReLU; K=256.

template <bool RELU>
__global__ __launch_bounds__(256) void sage_mfma_kernel(
    const unsigned short* __restrict__ Acat, const unsigned short* __restrict__ WT,
    const float* __restrict__ bias, unsigned short* __restrict__ out,
    int out_stride, int nnodes) {

    const int tid = threadIdx.x;
    const int w = tid >> 6, l = tid & 63;
    const int r16 = l & 15, g = l >> 4;
    const int rowbase = blockIdx.x * 64 + w * 16;

    f32x4 acc[8];
#pragma unroll
    for (int j = 0; j < 8; ++j) {
        float bj = bias[j * 16 + r16];
        acc[j] = (f32x4){bj, bj, bj, bj};
    }

    const unsigned short* ap = Acat + (size_t)(rowbase + r16) * 256 + g * 8;
    const unsigned short* bp = WT + (size_t)r16 * 256 + g * 8;

#pragma unroll
    for (int ks = 0; ks < 8; ++ks) {
        const short8 a = *reinterpret_cast<const short8*>(ap + ks * 32);
#pragma unroll
        for (int j = 0; j < 8; ++j) {
            const short8 b = *reinterpret_cast<const short8*>(bp + j * 4096 + ks * 32);
            acc[j] = __builtin_amdgcn_mfma_f32_16x16x32_bf16(a, b, acc[j], 0, 0, 0);
        }
    }

    float ss[4] = {0.f, 0.f, 0.f, 0.f};
#pragma unroll
    for (int j = 0; j < 8; ++j)
#pragma unroll
        for (int i = 0; i < 4; ++i) ss[i] += acc[j][i] * acc[j][i];
#pragma unroll
    for (int m = 1; m < 16; m <<= 1)
#pragma unroll
        for (int i = 0; i < 4; ++i) ss[i] += __shfl_xor(ss[i], m, 64);

#pragma unroll
    for (int i = 0; i < 4; ++i) {
        int row = rowbase + g * 4 + i;
        if (row >= nnodes) continue;
        float sc = 1.0f / fmaxf(sqrtf(ss[i]), 1e-12f);
#pragma unroll
        for (int j = 0; j < 8; ++j) {
            float v = acc[j][i] * sc;
            if (RELU) v = fmaxf(v, 0.f);
            out[(size_t)row * out_stride + j * 16 + r16] = f2b(v);
        }
    }
}

// ---------------- head: logits = h@Wfc + bfc, softmax over 2 classes ----------------

__global__ void head_kernel(const unsigned short* __restrict__ h, const float* __restrict__ Wfc,
                            const float* __restrict__ bfc, float* __restrict__ out, int nnodes) {
    int wid  = (blockIdx.x * blockDim.x + threadIdx.x) >> 6;
    int lane = threadIdx.x & 63;
    if (wid >= nnodes) return;
    float v0 = b2f(h[(size_t)wid * D + lane]);
    float v1 = b2f(h[(size_t)wid * D + 64 + lane]);
    float d0 = v0 * Wfc[lane * 2]       + v1 * Wfc[(lane + 64) * 2];
    float d1 = v0 * Wfc[lane * 2 + 1]   + v1 * Wfc[(lane + 64) * 2 + 1];
    for (int m = 1; m < 64; m <<= 1) {
        d0 += __shfl_xor(d0, m, 64);
        d1 += __shfl_xor(d1, m, 64);
    }
    if (lane == 0) {
        d0 += bfc[0]; d1 += bfc[1];
        float mx = fmaxf(d0, d1);
        float e0 = expf(d0 - mx), e1 = expf(d1 - mx);
        float inv = 1.0f / (e0 + e1);
        out[(size_t)wid * 2]     = e0 * inv;
        out[(size_t)wid * 2 + 1] = e1 * inv;
    }
}

// ---------------- launch ----------------

extern "C" void kernel_launch(void* const* d_in, const int* in_sizes, int n_in,
                              void* d_out, int out_size, void* d_ws, size_t ws_size,
                              hipStream_t stream) {
    const float* x   = (const float*)d_in[0];
    const int*   ei  = (const int*)d_in[1];
    const float* W1l = (const float*)d_in[2];
    const float* b1l = (const float*)d_in[3];
    const float* W1r = (const float*)d_in[4];
    const float* W2l = (const float*)d_in[5];
    const float* b2l = (const float*)d_in[6];
    const float* W2r = (const float*)d_in[7];
    const float* Wfc = (const float*)d_in[8];
    const float* bfc = (const float*)d_in[9];

    const int N = in_sizes[0] / D;
    const int E = in_sizes[1] / 2;
    const int* src = ei;        // edge_index[0]
    const int* dst = ei + E;    // edge_index[1]
    const int NBC = (N + (1 << CBITS) - 1) >> CBITS;     // coarse buckets (49), <=64

    // workspace: bf16 feature tables first (16B aligned), ints after
    unsigned short* Acat1 = (unsigned short*)d_ws;        // N x 256 : [agg1 | xb]
    unsigned short* Acat2 = Acat1 + (size_t)N * 256;      // N x 256 : [agg2 | h1]
    unsigned short* h2    = Acat1;                        // N x 128 (reuses Acat1; gemm2 reads only Acat2)
    int2* staging         = (int2*)Acat2;                 // E x int2 (dead until mfma1, aliasing safe)
    unsigned short* WT1   = Acat2 + (size_t)N * 256;      // 128 x 256
    unsigned short* WT2   = WT1 + 128 * 256;              // 128 x 256
    int* counts  = (int*)(WT2 + 128 * 256);               // N
    int* offsets = counts + N;                            // N+1
    int* cursor  = offsets + N + 1;                       // N
    int* cursorA = cursor + N;                            // NBC
    int* csr     = cursorA + NBC;                         // E
    int* partials = csr + E;                              // <=256

    const int nb_scan = (N + 1023) / 1024;

    hipMemsetAsync(counts, 0, (size_t)(3 * N + 1 + NBC) * sizeof(int), stream);

    // CSR build (count -> scan -> LDS-binned two-pass fill)
    count_kernel<<<(E + 255) / 256, 256, 0, stream>>>(dst, counts, E);
    scan_part_kernel<<<nb_scan, 256, 0, stream>>>(counts, partials, N);
    scan_base_kernel<<<1, 256, 0, stream>>>(partials, nb_scan, offsets, N);
    scan_write_kernel<<<nb_scan, 256, 0, stream>>>(counts, partials, offsets, N);
    bin_coarse_kernel<<<(E + 4095) / 4096, 256, 0, stream>>>(src, dst, offsets, cursorA, staging, E);
    bin_fine_kernel<<<(E + 255) / 256, 256, 0, stream>>>(staging, offsets, cursor, csr, E);

    // bf16 prep
    cast_x_kernel<<<(N * 16 + 255) / 256, 256, 0, stream>>>(x, Acat1, N * 16);
    prep_w_kernel<<<256, 256, 0, stream>>>(W1l, W1r, W2l, W2r, WT1, WT2);

    // layer 1: agg(xb) -> Acat1[:,0:128]; h1 = l2norm(Acat1@Wcat1+b) -> Acat2[:,128:256]
    aggregate_kernel<<<(N + 15) / 16, 256, 0, stream>>>(Acat1 + 128, offsets, csr, Acat1, N);
    sage_mfma_kernel<true><<<(N + 63) / 64, 256, 0, stream>>>(Acat1, WT1, b1l, Acat2 + 128, 256, N);

    // layer 2: agg(h1) -> Acat2[:,0:128]; h2 = l2norm(Acat2@Wcat2+b) -> h2 (stride 128)
    aggregate_kernel<<<(N + 15) / 16, 256, 0, stream>>>(Acat2 + 128, offsets, csr, Acat2, N);
    sage_mfma_kernel<false><<<(N + 63) / 64, 256, 0, stream>>>(Acat2, WT2, b2l, h2, D, N);

    // head + softmax
    head_kernel<<<(N + 3) / 4, 256, 0, stream>>>(h2, Wfc, bfc, (float*)d_out, N);
}

// Round 6
// 260.005 us; speedup vs baseline: 1.6743x; 1.0138x over previous
//
#include <hip/hip_runtime.h>

#define D 128
#define CBITS 10   // 1024 nodes per coarse bucket (<=64 buckets for N<=65536)

typedef __attribute__((ext_vector_type(8))) short short8;
typedef __attribute__((ext_vector_type(4))) float f32x4;

__device__ __forceinline__ unsigned short f2b(float f) {
    unsigned u = __builtin_bit_cast(unsigned, f);
    u += 0x7fffu + ((u >> 16) & 1u);           // round-to-nearest-even
    return (unsigned short)(u >> 16);
}
__device__ __forceinline__ float b2f(unsigned short b) {
    unsigned u = ((unsigned)b) << 16;
    return __builtin_bit_cast(float, u);
}

// ---------------- zero fill (rocclr fillBuffer was 41us for 600KB - R5 lesson) ----------------

__global__ void zero_kernel(int4* __restrict__ p, int n4) {
    int i = blockIdx.x * blockDim.x + threadIdx.x;
    if (i < n4) p[i] = make_int4(0, 0, 0, 0);
}

// ---------------- CSR build ----------------

__global__ void count_kernel(const int* __restrict__ dst, int* __restrict__ counts, int E) {
    int e = blockIdx.x * blockDim.x + threadIdx.x;
    if (e < E) atomicAdd(&counts[dst[e]], 1);
}

__global__ void scan_part_kernel(const int* __restrict__ counts, int* __restrict__ partials, int n) {
    __shared__ int lds[256];
    int t = threadIdx.x;
    int base = blockIdx.x * 1024 + t * 4;
    int s = 0;
    if (base + 3 < n) {
        int4 v = *reinterpret_cast<const int4*>(counts + base);
        s = v.x + v.y + v.z + v.w;
    } else {
        for (int i = 0; i < 4; ++i) if (base + i < n) s += counts[base + i];
    }
    lds[t] = s;
    __syncthreads();
    for (int d = 128; d > 0; d >>= 1) { if (t < d) lds[t] += lds[t + d]; __syncthreads(); }
    if (t == 0) partials[blockIdx.x] = lds[0];
}

__global__ void scan_base_kernel(int* __restrict__ partials, int nb, int* __restrict__ offsets, int n) {
    __shared__ int lds[256];
    int t = threadIdx.x;
    int v = (t < nb) ? partials[t] : 0;
    lds[t] = v;
    __syncthreads();
    for (int d = 1; d < 256; d <<= 1) {
        int u = (t >= d) ? lds[t - d] : 0;
        __syncthreads();
        lds[t] += u;
        __syncthreads();
    }
    if (t < nb) partials[t] = lds[t] - v;
    if (t == 255) offsets[n] = lds[255];
}

__global__ void scan_write_kernel(const int* __restrict__ counts, const int* __restrict__ partials,
                                  int* __restrict__ offsets, int n) {
    __shared__ int lds[256];
    int t = threadIdx.x;
    int base = blockIdx.x * 1024 + t * 4;
    int v[4];
    for (int i = 0; i < 4; ++i) v[i] = (base + i < n) ? counts[base + i] : 0;
    int s = v[0] + v[1] + v[2] + v[3];
    lds[t] = s;
    __syncthreads();
    for (int d = 1; d < 256; d <<= 1) {
        int u = (t >= d) ? lds[t - d] : 0;
        __syncthreads();
        lds[t] += u;
        __syncthreads();
    }
    int run = (t == 0 ? 0 : lds[t - 1]) + partials[blockIdx.x];
    for (int i = 0; i < 4; ++i) {
        if (base + i < n) offsets[base + i] = run;
        run += v[i];
    }
}

// Pass 1: coarse bucket sort with PER-BLOCK LDS histograms.
__global__ __launch_bounds__(256) void bin_coarse_kernel(
    const int* __restrict__ src, const int* __restrict__ dst,
    const int* __restrict__ offsets, int* __restrict__ cursorA,
    int2* __restrict__ staging, int E) {

    __shared__ int hist[64];
    __shared__ int lcur[64];
    const int t = threadIdx.x;
    if (t < 64) hist[t] = 0;
    __syncthreads();

    const int base = blockIdx.x * 4096;
    int sreg[16], dreg[16];
#pragma unroll
    for (int i = 0; i < 16; ++i) {
        int e = base + i * 256 + t;
        int s = 0, d = -1;
        if (e < E) {
            s = src[e]; d = dst[e];
            atomicAdd(&hist[d >> CBITS], 1);
        }
        sreg[i] = s; dreg[i] = d;
    }
    __syncthreads();
    if (t < 64) {
        int h = hist[t];
        lcur[t] = h ? atomicAdd(&cursorA[t], h) : 0;   // absolute base within bucket
    }
    __syncthreads();
#pragma unroll
    for (int i = 0; i < 16; ++i) {
        if (dreg[i] >= 0) {
            int b = dreg[i] >> CBITS;
            int p = atomicAdd(&lcur[b], 1);            // LDS atomic: cheap
            staging[offsets[b << CBITS] + p] = make_int2(sreg[i], dreg[i]);
        }
    }
}

// Pass 2: staging is bucket-grouped; csr scatter lands in a ~64KB window (L2-hit).
__global__ void bin_fine_kernel(const int2* __restrict__ staging, const int* __restrict__ offsets,
                                int* __restrict__ cursor, int* __restrict__ csr, int E) {
    int e = blockIdx.x * blockDim.x + threadIdx.x;
    if (e < E) {
        int2 sd = staging[e];
        int p = atomicAdd(&cursor[sd.y], 1);
        csr[offsets[sd.y] + p] = sd.x;
    }
}

// ---------------- bf16 prep ----------------

__global__ void cast_x_kernel(const float* __restrict__ x, unsigned short* __restrict__ acat, int n16) {
    int g = blockIdx.x * blockDim.x + threadIdx.x;   // one 8-elem chunk
    if (g >= n16) return;
    int row = g >> 4, chunk = g & 15;
    const float4 v0 = *reinterpret_cast<const float4*>(x + (size_t)g * 8);
    const float4 v1 = *reinterpret_cast<const float4*>(x + (size_t)g * 8 + 4);
    short8 r;
    r[0] = (short)f2b(v0.x); r[1] = (short)f2b(v0.y); r[2] = (short)f2b(v0.z); r[3] = (short)f2b(v0.w);
    r[4] = (short)f2b(v1.x); r[5] = (short)f2b(v1.y); r[6] = (short)f2b(v1.z); r[7] = (short)f2b(v1.w);
    *reinterpret_cast<short8*>(acat + (size_t)row * 256 + 128 + chunk * 8) = r;
}

__global__ void prep_w_kernel(const float* __restrict__ W1l, const float* __restrict__ W1r,
                              const float* __restrict__ W2l, const float* __restrict__ W2r,
                              unsigned short* __restrict__ WT1, unsigned short* __restrict__ WT2) {
    int layer = blockIdx.x >> 7;
    int j = blockIdx.x & 127;
    int k = threadIdx.x;  // 0..255
    const float* Wl = layer ? W2l : W1l;
    const float* Wr = layer ? W2r : W1r;
    unsigned short* WT = layer ? WT2 : WT1;
    float v = (k < 128) ? Wl[k * D + j] : Wr[(k - 128) * D + j];
    WT[(size_t)j * 256 + k] = f2b(v);
}

// ---------------- mean aggregation (bf16 gather, f32 accumulate) ----------------

__global__ void aggregate_kernel(const unsigned short* __restrict__ xin,   // row stride 256 (pre-offset +128)
                                 const int* __restrict__ offsets, const int* __restrict__ csr,
                                 unsigned short* __restrict__ out,         // row stride 256 (offset 0)
                                 int nnodes) {
    int node = blockIdx.x * 16 + (threadIdx.x >> 4);
    int l16 = threadIdx.x & 15;
    if (node >= nnodes) return;
    int lo = offsets[node], hi = offsets[node + 1];
    float acc[8] = {0.f, 0.f, 0.f, 0.f, 0.f, 0.f, 0.f, 0.f};
    for (int k = lo; k < hi; ++k) {
        int s = csr[k];
        const short8 v = *reinterpret_cast<const short8*>(xin + (size_t)s * 256 + l16 * 8);
        for (int i = 0; i < 8; ++i) acc[i] += b2f((unsigned short)v[i]);
    }
    float inv = 1.0f / fmaxf((float)(hi - lo), 1.0f);
    short8 r;
    for (int i = 0; i < 8; ++i) r[i] = (short)f2b(acc[i] * inv);
    *reinterpret_cast<short8*>(out + (size_t)node * 256 + l16 * 8) = r;
}

// ---------------- fused SAGE linear via MFMA ----------------
// out[n][0..127] = l2norm(Acat[n][0..255] @ Wcat + b), opt ReLU; K=256.

template <bool RELU>
__global__ __launch_bounds__(256) void sage_mfma_kernel(
    const unsigned short* __restrict__ Acat, const unsigned short* __restrict__ WT,
    const float* __restrict__ bias, unsigned short* __restrict__ out,
    int out_stride, int nnodes) {

    const int tid = threadIdx.x;
    const int w = tid >> 6, l = tid & 63;
    const int r16 = l & 15, g = l >> 4;
    const int rowbase = blockIdx.x * 64 + w * 16;

    f32x4 acc[8];
#pragma unroll
    for (int j = 0; j < 8; ++j) {
        float bj = bias[j * 16 + r16];
        acc[j] = (f32x4){bj, bj, bj, bj};
    }

    const unsigned short* ap = Acat + (size_t)(rowbase + r16) * 256 + g * 8;
    const unsigned short* bp = WT + (size_t)r16 * 256 + g * 8;

#pragma unroll
    for (int ks = 0; ks < 8; ++ks) {
        const short8 a = *reinterpret_cast<const short8*>(ap + ks * 32);
#pragma unroll
        for (int j = 0; j < 8; ++j) {
            const short8 b = *reinterpret_cast<const short8*>(bp + j * 4096 + ks * 32);
            acc[j] = __builtin_amdgcn_mfma_f32_16x16x32_bf16(a, b, acc[j], 0, 0, 0);
        }
    }

    float ss[4] = {0.f, 0.f, 0.f, 0.f};
#pragma unroll
    for (int j = 0; j < 8; ++j)
#pragma unroll
        for (int i = 0; i < 4; ++i) ss[i] += acc[j][i] * acc[j][i];
#pragma unroll
    for (int m = 1; m < 16; m <<= 1)
#pragma unroll
        for (int i = 0; i < 4; ++i) ss[i] += __shfl_xor(ss[i], m, 64);

#pragma unroll
    for (int i = 0; i < 4; ++i) {
        int row = rowbase + g * 4 + i;
        if (row >= nnodes) continue;
        float sc = 1.0f / fmaxf(sqrtf(ss[i]), 1e-12f);
#pragma unroll
        for (int j = 0; j < 8; ++j) {
            float v = acc[j][i] * sc;
            if (RELU) v = fmaxf(v, 0.f);
            out[(size_t)row * out_stride + j * 16 + r16] = f2b(v);
        }
    }
}

// ---------------- head: logits = h@Wfc + bfc, softmax over 2 classes ----------------

__global__ void head_kernel(const unsigned short* __restrict__ h, const float* __restrict__ Wfc,
                            const float* __restrict__ bfc, float* __restrict__ out, int nnodes) {
    int wid  = (blockIdx.x * blockDim.x + threadIdx.x) >> 6;
    int lane = threadIdx.x & 63;
    if (wid >= nnodes) return;
    float v0 = b2f(h[(size_t)wid * D + lane]);
    float v1 = b2f(h[(size_t)wid * D + 64 + lane]);
    float d0 = v0 * Wfc[lane * 2]       + v1 * Wfc[(lane + 64) * 2];
    float d1 = v0 * Wfc[lane * 2 + 1]   + v1 * Wfc[(lane + 64) * 2 + 1];
    for (int m = 1; m < 64; m <<= 1) {
        d0 += __shfl_xor(d0, m, 64);
        d1 += __shfl_xor(d1, m, 64);
    }
    if (lane == 0) {
        d0 += bfc[0]; d1 += bfc[1];
        float mx = fmaxf(d0, d1);
        float e0 = expf(d0 - mx), e1 = expf(d1 - mx);
        float inv = 1.0f / (e0 + e1);
        out[(size_t)wid * 2]     = e0 * inv;
        out[(size_t)wid * 2 + 1] = e1 * inv;
    }
}

// ---------------- launch ----------------

extern "C" void kernel_launch(void* const* d_in, const int* in_sizes, int n_in,
                              void* d_out, int out_size, void* d_ws, size_t ws_size,
                              hipStream_t stream) {
    const float* x   = (const float*)d_in[0];
    const int*   ei  = (const int*)d_in[1];
    const float* W1l = (const float*)d_in[2];
    const float* b1l = (const float*)d_in[3];
    const float* W1r = (const float*)d_in[4];
    const float* W2l = (const float*)d_in[5];
    const float* b2l = (const float*)d_in[6];
    const float* W2r = (const float*)d_in[7];
    const float* Wfc = (const float*)d_in[8];
    const float* bfc = (const float*)d_in[9];

    const int N = in_sizes[0] / D;
    const int E = in_sizes[1] / 2;
    const int* src = ei;        // edge_index[0]
    const int* dst = ei + E;    // edge_index[1]
    const int NBC = (N + (1 << CBITS) - 1) >> CBITS;     // coarse buckets (49), <=64

    // workspace: bf16 feature tables first (16B aligned), ints after.
    // counts/cursor/cursorA are CONTIGUOUS so one zero_kernel covers them.
    unsigned short* Acat1 = (unsigned short*)d_ws;        // N x 256 : [agg1 | xb]
    unsigned short* Acat2 = Acat1 + (size_t)N * 256;      // N x 256 : [agg2 | h1]
    unsigned short* h2    = Acat1;                        // N x 128 (reuses Acat1; gemm2 reads only Acat2)
    int2* staging         = (int2*)Acat2;                 // E x int2 (dead until mfma1, aliasing safe)
    unsigned short* WT1   = Acat2 + (size_t)N * 256;      // 128 x 256
    unsigned short* WT2   = WT1 + 128 * 256;              // 128 x 256
    int* counts  = (int*)(WT2 + 128 * 256);               // N      } zeroed
    int* cursor  = counts + N;                            // N      } zeroed
    int* cursorA = cursor + N;                            // NBC    } zeroed (pad to /4)
    int* offsets = cursorA + ((NBC + 3) & ~3);            // N+1
    int* csr     = offsets + N + 1;                       // E
    int* partials = csr + E;                              // <=256

    const int nb_scan = (N + 1023) / 1024;
    const int nzero4 = (2 * N + ((NBC + 3) & ~3)) / 4;    // int4 count (2N%4==0 for N=50000)

    // custom zero fill: rocclr fillBufferAligned took 41us/replay for 600KB (R5)
    zero_kernel<<<(nzero4 + 255) / 256, 256, 0, stream>>>((int4*)counts, nzero4);

    // CSR build (count -> scan -> LDS-binned two-pass fill)
    count_kernel<<<(E + 255) / 256, 256, 0, stream>>>(dst, counts, E);
    scan_part_kernel<<<nb_scan, 256, 0, stream>>>(counts, partials, N);
    scan_base_kernel<<<1, 256, 0, stream>>>(partials, nb_scan, offsets, N);
    scan_write_kernel<<<nb_scan, 256, 0, stream>>>(counts, partials, offsets, N);
    bin_coarse_kernel<<<(E + 4095) / 4096, 256, 0, stream>>>(src, dst, offsets, cursorA, staging, E);
    bin_fine_kernel<<<(E + 255) / 256, 256, 0, stream>>>(staging, offsets, cursor, csr, E);

    // bf16 prep
    cast_x_kernel<<<(N * 16 + 255) / 256, 256, 0, stream>>>(x, Acat1, N * 16);
    prep_w_kernel<<<256, 256, 0, stream>>>(W1l, W1r, W2l, W2r, WT1, WT2);

    // layer 1: agg(xb) -> Acat1[:,0:128]; h1 = l2norm(Acat1@Wcat1+b) -> Acat2[:,128:256]
    aggregate_kernel<<<(N + 15) / 16, 256, 0, stream>>>(Acat1 + 128, offsets, csr, Acat1, N);
    sage_mfma_kernel<true><<<(N + 63) / 64, 256, 0, stream>>>(Acat1, WT1, b1l, Acat2 + 128, 256, N);

    // layer 2: agg(h1) -> Acat2[:,0:128]; h2 = l2norm(Acat2@Wcat2+b) -> h2 (stride 128)
    aggregate_kernel<<<(N + 15) / 16, 256, 0, stream>>>(Acat2 + 128, offsets, csr, Acat2, N);
    sage_mfma_kernel<false><<<(N + 63) / 64, 256, 0, stream>>>(Acat2, WT2, b2l, h2, D, N);

    // head + softmax
    head_kernel<<<(N + 3) / 4, 256, 0, stream>>>(h2, Wfc, bfc, (float*)d_out, N);
}

// Round 7
// 189.473 us; speedup vs baseline: 2.2975x; 1.3723x over previous
//
#include <hip/hip_runtime.h>

#define D 128
#define CBITS 8    // 256 nodes per coarse bucket -> NBC = ceil(N/256) buckets (196 for N=50K)

typedef __attribute__((ext_vector_type(8))) short short8;
typedef __attribute__((ext_vector_type(4))) float f32x4;

__device__ __forceinline__ unsigned short f2b(float f) {
    unsigned u = __builtin_bit_cast(unsigned, f);
    u += 0x7fffu + ((u >> 16) & 1u);           // round-to-nearest-even
    return (unsigned short)(u >> 16);
}
__device__ __forceinline__ float b2f(unsigned short b) {
    unsigned u = ((unsigned)b) << 16;
    return __builtin_bit_cast(float, u);
}

// ---------------- zero fill (tiny: 512 ints) ----------------

__global__ void zero_kernel(int4* __restrict__ p, int n4) {
    int i = blockIdx.x * blockDim.x + threadIdx.x;
    if (i < n4) p[i] = make_int4(0, 0, 0, 0);
}

// ---------------- CSR build: zero per-edge global atomics ----------------
// bucket_count: per-block LDS hist of dst>>CBITS, one global add per (block,bucket).

__global__ __launch_bounds__(256) void bucket_count_kernel(
    const int* __restrict__ dst, int* __restrict__ bucketCnt, int E) {
    __shared__ int hist[256];
    const int t = threadIdx.x;
    hist[t] = 0;
    __syncthreads();
    const int base = blockIdx.x * 4096;
#pragma unroll
    for (int i = 0; i < 16; ++i) {
        int e = base + i * 256 + t;
        if (e < E) atomicAdd(&hist[dst[e] >> CBITS], 1);
    }
    __syncthreads();
    if (hist[t]) atomicAdd(&bucketCnt[t], hist[t]);
}

// bucket_scan: one block scans <=256 bucket counts -> exclusive bases.
__global__ void bucket_scan_kernel(const int* __restrict__ bucketCnt, int nb,
                                   int* __restrict__ bucketBase,
                                   int* __restrict__ offsets, int nnodes, int E) {
    __shared__ int lds[256];
    const int t = threadIdx.x;
    int v = (t < nb) ? bucketCnt[t] : 0;
    lds[t] = v;
    __syncthreads();
    for (int d = 1; d < 256; d <<= 1) {
        int u = (t >= d) ? lds[t - d] : 0;
        __syncthreads();
        lds[t] += u;
        __syncthreads();
    }
    if (t < nb) bucketBase[t] = lds[t] - v;
    if (t == 0) { bucketBase[nb] = E; offsets[nnodes] = E; }
}

// bin_coarse: LDS-privatized bucket scatter (R4 lesson: never 1 global atomic/edge).
__global__ __launch_bounds__(256) void bin_coarse_kernel(
    const int* __restrict__ src, const int* __restrict__ dst,
    const int* __restrict__ bucketBase, int* __restrict__ cursorA,
    int2* __restrict__ staging, int nb, int E) {

    __shared__ int hist[256];
    __shared__ int lcur[256];
    const int t = threadIdx.x;
    hist[t] = 0;
    __syncthreads();

    const int base = blockIdx.x * 4096;
    int sreg[16], dreg[16];
#pragma unroll
    for (int i = 0; i < 16; ++i) {
        int e = base + i * 256 + t;
        int s = 0, d = -1;
        if (e < E) {
            s = src[e]; d = dst[e];
            atomicAdd(&hist[d >> CBITS], 1);
        }
        sreg[i] = s; dreg[i] = d;
    }
    __syncthreads();
    if (t < nb) {
        int h = hist[t];
        lcur[t] = bucketBase[t] + (h ? atomicAdd(&cursorA[t], h) : 0);
    } else {
        lcur[t] = 0;
    }
    __syncthreads();
#pragma unroll
    for (int i = 0; i < 16; ++i) {
        if (dreg[i] >= 0) {
            int p = atomicAdd(&lcur[dreg[i] >> CBITS], 1);   // LDS atomic
            staging[p] = make_int2(sreg[i], dreg[i]);
        }
    }
}

// bucket_build: one block per bucket (256 nodes). Per-node histogram + scan + ordered
// scatter, ALL in LDS -> writes offsets and csr with zero global atomics.
__global__ __launch_bounds__(256) void bucket_build_kernel(
    const int2* __restrict__ staging, const int* __restrict__ bucketBase,
    int* __restrict__ offsets, int* __restrict__ csr, int nnodes) {

    __shared__ int hist[256];
    __shared__ int sc[256];
    __shared__ int lcur[256];
    const int t = threadIdx.x;
    const int b = blockIdx.x;
    const int base = bucketBase[b], end = bucketBase[b + 1];

    hist[t] = 0;
    __syncthreads();
    for (int i = base + t; i < end; i += 256)
        atomicAdd(&hist[staging[i].y & ((1 << CBITS) - 1)], 1);
    __syncthreads();
    sc[t] = hist[t];
    __syncthreads();
    for (int d = 1; d < 256; d <<= 1) {
        int u = (t >= d) ? sc[t - d] : 0;
        __syncthreads();
        sc[t] += u;
        __syncthreads();
    }
    const int excl = sc[t] - hist[t];
    const int node = (b << CBITS) + t;
    if (node < nnodes) offsets[node] = base + excl;
    lcur[t] = base + excl;
    __syncthreads();
    for (int i = base + t; i < end; i += 256) {
        int2 sd = staging[i];
        int p = atomicAdd(&lcur[sd.y & ((1 << CBITS) - 1)], 1);   // LDS atomic
        csr[p] = sd.x;
    }
}

// ---------------- bf16 prep ----------------

__global__ void cast_x_kernel(const float* __restrict__ x, unsigned short* __restrict__ acat, int n16) {
    int g = blockIdx.x * blockDim.x + threadIdx.x;   // one 8-elem chunk
    if (g >= n16) return;
    int row = g >> 4, chunk = g & 15;
    const float4 v0 = *reinterpret_cast<const float4*>(x + (size_t)g * 8);
    const float4 v1 = *reinterpret_cast<const float4*>(x + (size_t)g * 8 + 4);
    short8 r;
    r[0] = (short)f2b(v0.x); r[1] = (short)f2b(v0.y); r[2] = (short)f2b(v0.z); r[3] = (short)f2b(v0.w);
    r[4] = (short)f2b(v1.x); r[5] = (short)f2b(v1.y); r[6] = (short)f2b(v1.z); r[7] = (short)f2b(v1.w);
    *reinterpret_cast<short8*>(acat + (size_t)row * 256 + 128 + chunk * 8) = r;
}

__global__ void prep_w_kernel(const float* __restrict__ W1l, const float* __restrict__ W1r,
                              const float* __restrict__ W2l, const float* __restrict__ W2r,
                              unsigned short* __restrict__ WT1, unsigned short* __restrict__ WT2) {
    int layer = blockIdx.x >> 7;
    int j = blockIdx.x & 127;
    int k = threadIdx.x;  // 0..255
    const float* Wl = layer ? W2l : W1l;
    const float* Wr = layer ? W2r : W1r;
    unsigned short* WT = layer ? WT2 : WT1;
    float v = (k < 128) ? Wl[k * D + j] : Wr[(k - 128) * D + j];
    WT[(size_t)j * 256 + k] = f2b(v);
}

// ---------------- mean aggregation (bf16 gather, f32 accumulate) ----------------
// 16 lanes/node; neighbor loop unrolled x4: 4 independent csr reads + 4 row
// gathers in flight per group (64 lines/wave outstanding) - R6 was latency-bound.

__global__ __launch_bounds__(256) void aggregate_kernel(
    const unsigned short* __restrict__ xin,   // row stride 256 (pre-offset +128)
    const int* __restrict__ offsets, const int* __restrict__ csr,
    unsigned short* __restrict__ out,         // row stride 256 (offset 0)
    int nnodes) {
    int node = blockIdx.x * 16 + (threadIdx.x >> 4);
    int l16 = threadIdx.x & 15;
    if (node >= nnodes) return;
    int lo = offsets[node], hi = offsets[node + 1];
    float acc[8] = {0.f, 0.f, 0.f, 0.f, 0.f, 0.f, 0.f, 0.f};
    int k = lo;
    for (; k + 4 <= hi; k += 4) {
        int s0 = csr[k], s1 = csr[k + 1], s2 = csr[k + 2], s3 = csr[k + 3];
        const short8 v0 = *reinterpret_cast<const short8*>(xin + (size_t)s0 * 256 + l16 * 8);
        const short8 v1 = *reinterpret_cast<const short8*>(xin + (size_t)s1 * 256 + l16 * 8);
        const short8 v2 = *reinterpret_cast<const short8*>(xin + (size_t)s2 * 256 + l16 * 8);
        const short8 v3 = *reinterpret_cast<const short8*>(xin + (size_t)s3 * 256 + l16 * 8);
#pragma unroll
        for (int i = 0; i < 8; ++i)
            acc[i] += (b2f((unsigned short)v0[i]) + b2f((unsigned short)v1[i])) +
                      (b2f((unsigned short)v2[i]) + b2f((unsigned short)v3[i]));
    }
    for (; k < hi; ++k) {
        int s = csr[k];
        const short8 v = *reinterpret_cast<const short8*>(xin + (size_t)s * 256 + l16 * 8);
#pragma unroll
        for (int i = 0; i < 8; ++i) acc[i] += b2f((unsigned short)v[i]);
    }
    float inv = 1.0f / fmaxf((float)(hi - lo), 1.0f);
    short8 r;
#pragma unroll
    for (int i = 0; i < 8; ++i) r[i] = (short)f2b(acc[i] * inv);
    *reinterpret_cast<short8*>(out + (size_t)node * 256 + l16 * 8) = r;
}

// ---------------- fused SAGE linear via MFMA ----------------
// out[n][0..127] = l2norm(Acat[n][0..255] @ Wcat + b), opt ReLU; K=256.

template <bool RELU>
__global__ __launch_bounds__(256) void sage_mfma_kernel(
    const unsigned short* __restrict__ Acat, const unsigned short* __restrict__ WT,
    const float* __restrict__ bias, unsigned short* __restrict__ out,
    int out_stride, int nnodes) {

    const int tid = threadIdx.x;
    const int w = tid >> 6, l = tid & 63;
    const int r16 = l & 15, g = l >> 4;
    const int rowbase = blockIdx.x * 64 + w * 16;

    f32x4 acc[8];
#pragma unroll
    for (int j = 0; j < 8; ++j) {
        float bj = bias[j * 16 + r16];
        acc[j] = (f32x4){bj, bj, bj, bj};
    }

    const unsigned short* ap = Acat + (size_t)(rowbase + r16) * 256 + g * 8;
    const unsigned short* bp = WT + (size_t)r16 * 256 + g * 8;

#pragma unroll
    for (int ks = 0; ks < 8; ++ks) {
        const short8 a = *reinterpret_cast<const short8*>(ap + ks * 32);
#pragma unroll
        for (int j = 0; j < 8; ++j) {
            const short8 b = *reinterpret_cast<const short8*>(bp + j * 4096 + ks * 32);
            acc[j] = __builtin_amdgcn_mfma_f32_16x16x32_bf16(a, b, acc[j], 0, 0, 0);
        }
    }

    float ss[4] = {0.f, 0.f, 0.f, 0.f};
#pragma unroll
    for (int j = 0; j < 8; ++j)
#pragma unroll
        for (int i = 0; i < 4; ++i) ss[i] += acc[j][i] * acc[j][i];
#pragma unroll
    for (int m = 1; m < 16; m <<= 1)
#pragma unroll
        for (int i = 0; i < 4; ++i) ss[i] += __shfl_xor(ss[i], m, 64);

#pragma unroll
    for (int i = 0; i < 4; ++i) {
        int row = rowbase + g * 4 + i;
        if (row >= nnodes) continue;
        float sc = 1.0f / fmaxf(sqrtf(ss[i]), 1e-12f);
#pragma unroll
        for (int j = 0; j < 8; ++j) {
            float v = acc[j][i] * sc;
            if (RELU) v = fmaxf(v, 0.f);
            out[(size_t)row * out_stride + j * 16 + r16] = f2b(v);
        }
    }
}

// ---------------- head: logits = h@Wfc + bfc, softmax over 2 classes ----------------

__global__ void head_kernel(const unsigned short* __restrict__ h, const float* __restrict__ Wfc,
                            const float* __restrict__ bfc, float* __restrict__ out, int nnodes) {
    int wid  = (blockIdx.x * blockDim.x + threadIdx.x) >> 6;
    int lane = threadIdx.x & 63;
    if (wid >= nnodes) return;
    float v0 = b2f(h[(size_t)wid * D + lane]);
    float v1 = b2f(h[(size_t)wid * D + 64 + lane]);
    float d0 = v0 * Wfc[lane * 2]       + v1 * Wfc[(lane + 64) * 2];
    float d1 = v0 * Wfc[lane * 2 + 1]   + v1 * Wfc[(lane + 64) * 2 + 1];
    for (int m = 1; m < 64; m <<= 1) {
        d0 += __shfl_xor(d0, m, 64);
        d1 += __shfl_xor(d1, m, 64);
    }
    if (lane == 0) {
        d0 += bfc[0]; d1 += bfc[1];
        float mx = fmaxf(d0, d1);
        float e0 = expf(d0 - mx), e1 = expf(d1 - mx);
        float inv = 1.0f / (e0 + e1);
        out[(size_t)wid * 2]     = e0 * inv;
        out[(size_t)wid * 2 + 1] = e1 * inv;
    }
}

// ---------------- launch ----------------

extern "C" void kernel_launch(void* const* d_in, const int* in_sizes, int n_in,
                              void* d_out, int out_size, void* d_ws, size_t ws_size,
                              hipStream_t stream) {
    const float* x   = (const float*)d_in[0];
    const int*   ei  = (const int*)d_in[1];
    const float* W1l = (const float*)d_in[2];
    const float* b1l = (const float*)d_in[3];
    const float* W1r = (const float*)d_in[4];
    const float* W2l = (const float*)d_in[5];
    const float* b2l = (const float*)d_in[6];
    const float* W2r = (const float*)d_in[7];
    const float* Wfc = (const float*)d_in[8];
    const float* bfc = (const float*)d_in[9];

    const int N = in_sizes[0] / D;
    const int E = in_sizes[1] / 2;
    const int* src = ei;        // edge_index[0]
    const int* dst = ei + E;    // edge_index[1]
    const int NBC = (N + (1 << CBITS) - 1) >> CBITS;     // coarse buckets (196), <=256

    // workspace: bf16 feature tables first (16B aligned), ints after.
    unsigned short* Acat1 = (unsigned short*)d_ws;        // N x 256 : [agg1 | xb]
    unsigned short* Acat2 = Acat1 + (size_t)N * 256;      // N x 256 : [agg2 | h1]
    unsigned short* h2    = Acat1;                        // N x 128 (reuses Acat1; gemm2 reads only Acat2)
    int2* staging         = (int2*)Acat2;                 // E x int2 (dead until mfma1, aliasing safe)
    unsigned short* WT1   = Acat2 + (size_t)N * 256;      // 128 x 256
    unsigned short* WT2   = WT1 + 128 * 256;              // 128 x 256
    int* bucketCnt  = (int*)(WT2 + 128 * 256);            // 256 } zeroed together
    int* cursorA    = bucketCnt + 256;                    // 256 } (512 ints)
    int* bucketBase = cursorA + 256;                      // NBC+1 (<=257), padded
    int* offsets    = bucketBase + 260;                   // N+1
    int* csr        = offsets + N + 1;                    // E

    // tiny zero (R5/R6 lesson: hipMemsetAsync -> rocclr fill; keep our own, and keep it small)
    zero_kernel<<<1, 128, 0, stream>>>((int4*)bucketCnt, 128);

    // CSR build: zero per-edge global atomics
    bucket_count_kernel<<<(E + 4095) / 4096, 256, 0, stream>>>(dst, bucketCnt, E);
    bucket_scan_kernel<<<1, 256, 0, stream>>>(bucketCnt, NBC, bucketBase, offsets, N, E);
    bin_coarse_kernel<<<(E + 4095) / 4096, 256, 0, stream>>>(src, dst, bucketBase, cursorA, staging, NBC, E);
    bucket_build_kernel<<<NBC, 256, 0, stream>>>(staging, bucketBase, offsets, csr, N);

    // bf16 prep
    cast_x_kernel<<<(N * 16 + 255) / 256, 256, 0, stream>>>(x, Acat1, N * 16);
    prep_w_kernel<<<256, 256, 0, stream>>>(W1l, W1r, W2l, W2r, WT1, WT2);

    // layer 1: agg(xb) -> Acat1[:,0:128]; h1 = l2norm(Acat1@Wcat1+b) -> Acat2[:,128:256]
    aggregate_kernel<<<(N + 15) / 16, 256, 0, stream>>>(Acat1 + 128, offsets, csr, Acat1, N);
    sage_mfma_kernel<true><<<(N + 63) / 64, 256, 0, stream>>>(Acat1, WT1, b1l, Acat2 + 128, 256, N);

    // layer 2: agg(h1) -> Acat2[:,0:128]; h2 = l2norm(Acat2@Wcat2+b) -> h2 (stride 128)
    aggregate_kernel<<<(N + 15) / 16, 256, 0, stream>>>(Acat2 + 128, offsets, csr, Acat2, N);
    sage_mfma_kernel<false><<<(N + 63) / 64, 256, 0, stream>>>(Acat2, WT2, b2l, h2, D, N);

    // head + softmax
    head_kernel<<<(N + 3) / 4, 256, 0, stream>>>(h2, Wfc, bfc, (float*)d_out, N);
}

// Round 8
// 187.323 us; speedup vs baseline: 2.3239x; 1.0115x over previous
//
#include <hip/hip_runtime.h>

#define D 128
#define CBITS 8    // 256 nodes per coarse bucket

typedef __attribute__((ext_vector_type(8))) short short8;
typedef __attribute__((ext_vector_type(4))) float f32x4;

__device__ __forceinline__ unsigned short f2b(float f) {
    unsigned u = __builtin_bit_cast(unsigned, f);
    u += 0x7fffu + ((u >> 16) & 1u);           // round-to-nearest-even
    return (unsigned short)(u >> 16);
}
__device__ __forceinline__ float b2f(unsigned short b) {
    unsigned u = ((unsigned)b) << 16;
    return __builtin_bit_cast(float, u);
}

// ---------------- combined prep: cast x->bf16, W->WT bf16, zero counters ----------------

__global__ __launch_bounds__(256) void prep_kernel(
    const float* __restrict__ x, unsigned short* __restrict__ xb, int nCast, int n8,
    const float* __restrict__ W1l, const float* __restrict__ W1r,
    const float* __restrict__ W2l, const float* __restrict__ W2r,
    unsigned short* __restrict__ WT1, unsigned short* __restrict__ WT2,
    int4* __restrict__ zeroPtr) {
    const int b = blockIdx.x;
    if (b < nCast) {
        int g = b * 256 + threadIdx.x;
        if (g < n8) {
            const float4 v0 = *reinterpret_cast<const float4*>(x + (size_t)g * 8);
            const float4 v1 = *reinterpret_cast<const float4*>(x + (size_t)g * 8 + 4);
            short8 r;
            r[0] = (short)f2b(v0.x); r[1] = (short)f2b(v0.y); r[2] = (short)f2b(v0.z); r[3] = (short)f2b(v0.w);
            r[4] = (short)f2b(v1.x); r[5] = (short)f2b(v1.y); r[6] = (short)f2b(v1.z); r[7] = (short)f2b(v1.w);
            *reinterpret_cast<short8*>(xb + (size_t)g * 8) = r;
        }
    } else if (b < nCast + 256) {
        int bb = b - nCast;
        int layer = bb >> 7;
        int j = bb & 127;
        int k = threadIdx.x;  // 0..255
        const float* Wl = layer ? W2l : W1l;
        const float* Wr = layer ? W2r : W1r;
        unsigned short* WT = layer ? WT2 : WT1;
        float v = (k < 128) ? Wl[k * D + j] : Wr[(k - 128) * D + j];
        WT[(size_t)j * 256 + k] = f2b(v);
    } else {
        if (threadIdx.x < 128) zeroPtr[threadIdx.x] = make_int4(0, 0, 0, 0);
    }
}

// ---------------- CSR build: zero per-edge global atomics ----------------

__global__ __launch_bounds__(256) void bucket_count_kernel(
    const int* __restrict__ dst, int* __restrict__ bucketCnt, int E) {
    __shared__ int hist[256];
    const int t = threadIdx.x;
    hist[t] = 0;
    __syncthreads();
    const int base = blockIdx.x * 4096;
#pragma unroll
    for (int i = 0; i < 16; ++i) {
        int e = base + i * 256 + t;
        if (e < E) atomicAdd(&hist[dst[e] >> CBITS], 1);
    }
    __syncthreads();
    if (hist[t]) atomicAdd(&bucketCnt[t], hist[t]);
}

__global__ void bucket_scan_kernel(const int* __restrict__ bucketCnt, int nb,
                                   int* __restrict__ bucketBase,
                                   int* __restrict__ offsets, int nnodes, int E) {
    __shared__ int lds[256];
    const int t = threadIdx.x;
    int v = (t < nb) ? bucketCnt[t] : 0;
    lds[t] = v;
    __syncthreads();
    for (int d = 1; d < 256; d <<= 1) {
        int u = (t >= d) ? lds[t - d] : 0;
        __syncthreads();
        lds[t] += u;
        __syncthreads();
    }
    if (t < nb) bucketBase[t] = lds[t] - v;
    if (t == 0) { bucketBase[nb] = E; offsets[nnodes] = E; }
}

__global__ __launch_bounds__(256) void bin_coarse_kernel(
    const int* __restrict__ src, const int* __restrict__ dst,
    const int* __restrict__ bucketBase, int* __restrict__ cursorA,
    int2* __restrict__ staging, int nb, int E) {

    __shared__ int hist[256];
    __shared__ int lcur[256];
    const int t = threadIdx.x;
    hist[t] = 0;
    __syncthreads();

    const int base = blockIdx.x * 4096;
    int sreg[16], dreg[16];
#pragma unroll
    for (int i = 0; i < 16; ++i) {
        int e = base + i * 256 + t;
        int s = 0, d = -1;
        if (e < E) {
            s = src[e]; d = dst[e];
            atomicAdd(&hist[d >> CBITS], 1);
        }
        sreg[i] = s; dreg[i] = d;
    }
    __syncthreads();
    if (t < nb) {
        int h = hist[t];
        lcur[t] = bucketBase[t] + (h ? atomicAdd(&cursorA[t], h) : 0);
    } else {
        lcur[t] = 0;
    }
    __syncthreads();
#pragma unroll
    for (int i = 0; i < 16; ++i) {
        if (dreg[i] >= 0) {
            int p = atomicAdd(&lcur[dreg[i] >> CBITS], 1);   // LDS atomic
            staging[p] = make_int2(sreg[i], dreg[i]);
        }
    }
}

__global__ __launch_bounds__(256) void bucket_build_kernel(
    const int2* __restrict__ staging, const int* __restrict__ bucketBase,
    int* __restrict__ offsets, int* __restrict__ csr, int nnodes) {

    __shared__ int hist[256];
    __shared__ int sc[256];
    __shared__ int lcur[256];
    const int t = threadIdx.x;
    const int b = blockIdx.x;
    const int base = bucketBase[b], end = bucketBase[b + 1];

    hist[t] = 0;
    __syncthreads();
    for (int i = base + t; i < end; i += 256)
        atomicAdd(&hist[staging[i].y & ((1 << CBITS) - 1)], 1);
    __syncthreads();
    sc[t] = hist[t];
    __syncthreads();
    for (int d = 1; d < 256; d <<= 1) {
        int u = (t >= d) ? sc[t - d] : 0;
        __syncthreads();
        sc[t] += u;
        __syncthreads();
    }
    const int excl = sc[t] - hist[t];
    const int node = (b << CBITS) + t;
    if (node < nnodes) offsets[node] = base + excl;
    lcur[t] = base + excl;
    __syncthreads();
    for (int i = base + t; i < end; i += 256) {
        int2 sd = staging[i];
        int p = atomicAdd(&lcur[sd.y & ((1 << CBITS) - 1)], 1);   // LDS atomic
        csr[p] = sd.x;
    }
}

// ---------------- fused SAGE layer: gather-mean -> LDS -> MFMA -> norm -> epilogue ----------
// Block = 256 threads (4 waves) x 64 nodes. Phase 1: each wave gather-means 16 nodes
// (16 lanes/node, x4 unroll) into a swizzled LDS tile (T2: byte ^= (row&7)<<4 breaks the
// 16-rows-same-column conflict). Phase 2: K=256 MFMA, ks 0-3 A from LDS (agg), ks 4-7 A
// streamed from global feature rows (self term). Epilogue: l2norm + (relu | head+softmax).

template <int LAYER>
__global__ __launch_bounds__(256) void fused_sage_kernel(
    const unsigned short* __restrict__ xin,   // N x 128 bf16 (gather + self table)
    const int* __restrict__ offsets, const int* __restrict__ csr,
    const unsigned short* __restrict__ WT,    // 128 x 256
    const float* __restrict__ bias,
    unsigned short* __restrict__ hout,        // LAYER==1: N x 128 out
    const float* __restrict__ Wfc, const float* __restrict__ bfc,
    float* __restrict__ out,                  // LAYER==2: N x 2 softmax out
    int nnodes) {

    __shared__ unsigned short aT[64 * 128];   // 16 KB, swizzled rows
    const int tid = threadIdx.x;
    const int w = tid >> 6, l = tid & 63;
    const int r16 = l & 15, g = l >> 4;
    const int rowbase = blockIdx.x * 64;

    // ---- Phase 1: gather-mean ----
#pragma unroll
    for (int rep = 0; rep < 4; ++rep) {
        const int nl = w * 16 + rep * 4 + g;          // local node 0..63
        const int node = rowbase + nl;
        float acc[8] = {0.f, 0.f, 0.f, 0.f, 0.f, 0.f, 0.f, 0.f};
        int lo = 0, hi = 0;
        if (node < nnodes) { lo = offsets[node]; hi = offsets[node + 1]; }
        int k = lo;
        for (; k + 4 <= hi; k += 4) {
            int s0 = csr[k], s1 = csr[k + 1], s2 = csr[k + 2], s3 = csr[k + 3];
            const short8 v0 = *reinterpret_cast<const short8*>(xin + (size_t)s0 * 128 + r16 * 8);
            const short8 v1 = *reinterpret_cast<const short8*>(xin + (size_t)s1 * 128 + r16 * 8);
            const short8 v2 = *reinterpret_cast<const short8*>(xin + (size_t)s2 * 128 + r16 * 8);
            const short8 v3 = *reinterpret_cast<const short8*>(xin + (size_t)s3 * 128 + r16 * 8);
#pragma unroll
            for (int i = 0; i < 8; ++i)
                acc[i] += (b2f((unsigned short)v0[i]) + b2f((unsigned short)v1[i])) +
                          (b2f((unsigned short)v2[i]) + b2f((unsigned short)v3[i]));
        }
        for (; k < hi; ++k) {
            int s = csr[k];
            const short8 v = *reinterpret_cast<const short8*>(xin + (size_t)s * 128 + r16 * 8);
#pragma unroll
            for (int i = 0; i < 8; ++i) acc[i] += b2f((unsigned short)v[i]);
        }
        float inv = 1.0f / fmaxf((float)(hi - lo), 1.0f);
        short8 r;
#pragma unroll
        for (int i = 0; i < 8; ++i) r[i] = (short)f2b(acc[i] * inv);
        int boff = nl * 256 + ((r16 * 16) ^ ((nl & 7) << 4));   // swizzled
        *reinterpret_cast<short8*>(reinterpret_cast<char*>(aT) + boff) = r;
    }
    __syncthreads();

    // ---- Phase 2: MFMA, K=256 ----
    f32x4 acc[8];
#pragma unroll
    for (int j = 0; j < 8; ++j) {
        float bj = bias[j * 16 + r16];
        acc[j] = (f32x4){bj, bj, bj, bj};
    }

    const int arow = w * 16 + r16;                   // local A row this lane supplies
    int grow = rowbase + arow;
    if (grow >= nnodes) grow = 0;                    // clamp; garbage confined to unwritten rows
    const unsigned short* xp = xin + (size_t)grow * 128 + g * 8;
    const unsigned short* bp = WT + (size_t)r16 * 256 + g * 8;

#pragma unroll
    for (int ks = 0; ks < 8; ++ks) {
        short8 a;
        if (ks < 4) {
            int boff = arow * 256 + (((ks * 64) + g * 16) ^ ((arow & 7) << 4));
            a = *reinterpret_cast<const short8*>(reinterpret_cast<const char*>(aT) + boff);
        } else {
            a = *reinterpret_cast<const short8*>(xp + (ks - 4) * 32);
        }
#pragma unroll
        for (int j = 0; j < 8; ++j) {
            const short8 b = *reinterpret_cast<const short8*>(bp + j * 4096 + ks * 32);
            acc[j] = __builtin_amdgcn_mfma_f32_16x16x32_bf16(a, b, acc[j], 0, 0, 0);
        }
    }

    // ---- l2 norm (per output row; cols spread over 16 lanes x 8 tiles) ----
    float ss[4] = {0.f, 0.f, 0.f, 0.f};
#pragma unroll
    for (int j = 0; j < 8; ++j)
#pragma unroll
        for (int i = 0; i < 4; ++i) ss[i] += acc[j][i] * acc[j][i];
#pragma unroll
    for (int m = 1; m < 16; m <<= 1)
#pragma unroll
        for (int i = 0; i < 4; ++i) ss[i] += __shfl_xor(ss[i], m, 64);

    if (LAYER == 1) {
#pragma unroll
        for (int i = 0; i < 4; ++i) {
            int row = rowbase + w * 16 + g * 4 + i;
            if (row >= nnodes) continue;
            float sc = 1.0f / fmaxf(sqrtf(ss[i]), 1e-12f);
#pragma unroll
            for (int j = 0; j < 8; ++j) {
                float v = fmaxf(acc[j][i] * sc, 0.f);   // relu
                hout[(size_t)row * 128 + j * 16 + r16] = f2b(v);
            }
        }
    } else {
        // head: logits = h @ Wfc + bfc, softmax over 2 classes (no h2 table)
        float w0[8], w1[8];
#pragma unroll
        for (int j = 0; j < 8; ++j) {
            const float2 wv = *reinterpret_cast<const float2*>(Wfc + (j * 16 + r16) * 2);
            w0[j] = wv.x; w1[j] = wv.y;
        }
        const float b0 = bfc[0], b1 = bfc[1];
#pragma unroll
        for (int i = 0; i < 4; ++i) {
            float sc = 1.0f / fmaxf(sqrtf(ss[i]), 1e-12f);
            float l0 = 0.f, l1 = 0.f;
#pragma unroll
            for (int j = 0; j < 8; ++j) {
                float v = acc[j][i] * sc;
                l0 = fmaf(v, w0[j], l0);
                l1 = fmaf(v, w1[j], l1);
            }
#pragma unroll
            for (int m = 1; m < 16; m <<= 1) {
                l0 += __shfl_xor(l0, m, 64);
                l1 += __shfl_xor(l1, m, 64);
            }
            int row = rowbase + w * 16 + g * 4 + i;
            if (r16 == 0 && row < nnodes) {
                float d0 = l0 + b0, d1 = l1 + b1;
                float mx = fmaxf(d0, d1);
                float e0 = expf(d0 - mx), e1 = expf(d1 - mx);
                float inv = 1.0f / (e0 + e1);
                out[(size_t)row * 2]     = e0 * inv;
                out[(size_t)row * 2 + 1] = e1 * inv;
            }
        }
    }
}

// ---------------- launch ----------------

extern "C" void kernel_launch(void* const* d_in, const int* in_sizes, int n_in,
                              void* d_out, int out_size, void* d_ws, size_t ws_size,
                              hipStream_t stream) {
    const float* x   = (const float*)d_in[0];
    const int*   ei  = (const int*)d_in[1];
    const float* W1l = (const float*)d_in[2];
    const float* b1l = (const float*)d_in[3];
    const float* W1r = (const float*)d_in[4];
    const float* W2l = (const float*)d_in[5];
    const float* b2l = (const float*)d_in[6];
    const float* W2r = (const float*)d_in[7];
    const float* Wfc = (const float*)d_in[8];
    const float* bfc = (const float*)d_in[9];

    const int N = in_sizes[0] / D;
    const int E = in_sizes[1] / 2;
    const int* src = ei;        // edge_index[0]
    const int* dst = ei + E;    // edge_index[1]
    const int NBC = (N + (1 << CBITS) - 1) >> CBITS;     // coarse buckets (196), <=256

    // workspace layout (16B-aligned bf16 tables first)
    unsigned short* xb  = (unsigned short*)d_ws;          // N x 128 bf16
    unsigned short* h1  = xb + (size_t)N * 128;           // N x 128 bf16
    int2* staging       = (int2*)h1;                      // E x int2 aliases h1 (dead until fused1)
    unsigned short* WT1 = h1 + (size_t)N * 128;           // 128 x 256
    unsigned short* WT2 = WT1 + 128 * 256;                // 128 x 256
    int* bucketCnt  = (int*)(WT2 + 128 * 256);            // 256 } zeroed together (512 ints)
    int* cursorA    = bucketCnt + 256;                    // 256 }
    int* bucketBase = cursorA + 256;                      // NBC+1, padded to 260
    int* offsets    = bucketBase + 260;                   // N+1
    int* csr        = offsets + N + 1;                    // E

    const int nCast = (N * 16 + 255) / 256;

    // prep: cast x, transpose weights, zero counters (one launch)
    prep_kernel<<<nCast + 256 + 1, 256, 0, stream>>>(
        x, xb, nCast, N * 16, W1l, W1r, W2l, W2r, WT1, WT2, (int4*)bucketCnt);

    // CSR build: zero per-edge global atomics
    bucket_count_kernel<<<(E + 4095) / 4096, 256, 0, stream>>>(dst, bucketCnt, E);
    bucket_scan_kernel<<<1, 256, 0, stream>>>(bucketCnt, NBC, bucketBase, offsets, N, E);
    bin_coarse_kernel<<<(E + 4095) / 4096, 256, 0, stream>>>(src, dst, bucketBase, cursorA, staging, NBC, E);
    bucket_build_kernel<<<NBC, 256, 0, stream>>>(staging, bucketBase, offsets, csr, N);

    // fused layers
    fused_sage_kernel<1><<<(N + 63) / 64, 256, 0, stream>>>(
        xb, offsets, csr, WT1, b1l, h1, nullptr, nullptr, nullptr, N);
    fused_sage_kernel<2><<<(N + 63) / 64, 256, 0, stream>>>(
        h1, offsets, csr, WT2, b2l, nullptr, Wfc, bfc, (float*)d_out, N);
}

// Round 9
// 181.663 us; speedup vs baseline: 2.3963x; 1.0312x over previous
//
#include <hip/hip_runtime.h>

#define D 128
#define CBITS 8    // 256 nodes per coarse bucket

typedef __attribute__((ext_vector_type(8))) short short8;
typedef __attribute__((ext_vector_type(4))) float f32x4;

__device__ __forceinline__ unsigned short f2b(float f) {
    unsigned u = __builtin_bit_cast(unsigned, f);
    u += 0x7fffu + ((u >> 16) & 1u);           // round-to-nearest-even
    return (unsigned short)(u >> 16);
}
__device__ __forceinline__ float b2f(unsigned short b) {
    unsigned u = ((unsigned)b) << 16;
    return __builtin_bit_cast(float, u);
}

// ---------------- combined prep: cast x -> Acat1[:,128:], W->WT bf16, zero counters --------

__global__ __launch_bounds__(256) void prep_kernel(
    const float* __restrict__ x, unsigned short* __restrict__ acat, int nCast, int n8,
    const float* __restrict__ W1l, const float* __restrict__ W1r,
    const float* __restrict__ W2l, const float* __restrict__ W2r,
    unsigned short* __restrict__ WT1, unsigned short* __restrict__ WT2,
    int4* __restrict__ zeroPtr) {
    const int b = blockIdx.x;
    if (b < nCast) {
        int g = b * 256 + threadIdx.x;
        if (g < n8) {
            int row = g >> 4, chunk = g & 15;
            const float4 v0 = *reinterpret_cast<const float4*>(x + (size_t)g * 8);
            const float4 v1 = *reinterpret_cast<const float4*>(x + (size_t)g * 8 + 4);
            short8 r;
            r[0] = (short)f2b(v0.x); r[1] = (short)f2b(v0.y); r[2] = (short)f2b(v0.z); r[3] = (short)f2b(v0.w);
            r[4] = (short)f2b(v1.x); r[5] = (short)f2b(v1.y); r[6] = (short)f2b(v1.z); r[7] = (short)f2b(v1.w);
            *reinterpret_cast<short8*>(acat + (size_t)row * 256 + 128 + chunk * 8) = r;
        }
    } else if (b < nCast + 256) {
        int bb = b - nCast;
        int layer = bb >> 7;
        int j = bb & 127;
        int k = threadIdx.x;  // 0..255
        const float* Wl = layer ? W2l : W1l;
        const float* Wr = layer ? W2r : W1r;
        unsigned short* WT = layer ? WT2 : WT1;
        float v = (k < 128) ? Wl[k * D + j] : Wr[(k - 128) * D + j];
        WT[(size_t)j * 256 + k] = f2b(v);
    } else {
        if (threadIdx.x < 128) zeroPtr[threadIdx.x] = make_int4(0, 0, 0, 0);
    }
}

// ---------------- CSR build: zero per-edge global atomics ----------------

__global__ __launch_bounds__(256) void bucket_count_kernel(
    const int* __restrict__ dst, int* __restrict__ bucketCnt, int E) {
    __shared__ int hist[256];
    const int t = threadIdx.x;
    hist[t] = 0;
    __syncthreads();
    const int base = blockIdx.x * 4096;
#pragma unroll
    for (int i = 0; i < 16; ++i) {
        int e = base + i * 256 + t;
        if (e < E) atomicAdd(&hist[dst[e] >> CBITS], 1);
    }
    __syncthreads();
    if (hist[t]) atomicAdd(&bucketCnt[t], hist[t]);
}

__global__ void bucket_scan_kernel(const int* __restrict__ bucketCnt, int nb,
                                   int* __restrict__ bucketBase,
                                   int* __restrict__ offsets, int nnodes, int E) {
    __shared__ int lds[256];
    const int t = threadIdx.x;
    int v = (t < nb) ? bucketCnt[t] : 0;
    lds[t] = v;
    __syncthreads();
    for (int d = 1; d < 256; d <<= 1) {
        int u = (t >= d) ? lds[t - d] : 0;
        __syncthreads();
        lds[t] += u;
        __syncthreads();
    }
    if (t < nb) bucketBase[t] = lds[t] - v;
    if (t == 0) { bucketBase[nb] = E; offsets[nnodes] = E; }
}

__global__ __launch_bounds__(256) void bin_coarse_kernel(
    const int* __restrict__ src, const int* __restrict__ dst,
    const int* __restrict__ bucketBase, int* __restrict__ cursorA,
    int2* __restrict__ staging, int nb, int E) {

    __shared__ int hist[256];
    __shared__ int lcur[256];
    const int t = threadIdx.x;
    hist[t] = 0;
    __syncthreads();

    const int base = blockIdx.x * 4096;
    int sreg[16], dreg[16];
#pragma unroll
    for (int i = 0; i < 16; ++i) {
        int e = base + i * 256 + t;
        int s = 0, d = -1;
        if (e < E) {
            s = src[e]; d = dst[e];
            atomicAdd(&hist[d >> CBITS], 1);
        }
        sreg[i] = s; dreg[i] = d;
    }
    __syncthreads();
    if (t < nb) {
        int h = hist[t];
        lcur[t] = bucketBase[t] + (h ? atomicAdd(&cursorA[t], h) : 0);
    } else {
        lcur[t] = 0;
    }
    __syncthreads();
#pragma unroll
    for (int i = 0; i < 16; ++i) {
        if (dreg[i] >= 0) {
            int p = atomicAdd(&lcur[dreg[i] >> CBITS], 1);   // LDS atomic
            staging[p] = make_int2(sreg[i], dreg[i]);
        }
    }
}

__global__ __launch_bounds__(256) void bucket_build_kernel(
    const int2* __restrict__ staging, const int* __restrict__ bucketBase,
    int* __restrict__ offsets, int* __restrict__ csr, int nnodes) {

    __shared__ int hist[256];
    __shared__ int sc[256];
    __shared__ int lcur[256];
    const int t = threadIdx.x;
    const int b = blockIdx.x;
    const int base = bucketBase[b], end = bucketBase[b + 1];

    hist[t] = 0;
    __syncthreads();
    for (int i = base + t; i < end; i += 256)
        atomicAdd(&hist[staging[i].y & ((1 << CBITS) - 1)], 1);
    __syncthreads();
    sc[t] = hist[t];
    __syncthreads();
    for (int d = 1; d < 256; d <<= 1) {
        int u = (t >= d) ? sc[t - d] : 0;
        __syncthreads();
        sc[t] += u;
        __syncthreads();
    }
    const int excl = sc[t] - hist[t];
    const int node = (b << CBITS) + t;
    if (node < nnodes) offsets[node] = base + excl;
    lcur[t] = base + excl;
    __syncthreads();
    for (int i = base + t; i < end; i += 256) {
        int2 sd = staging[i];
        int p = atomicAdd(&lcur[sd.y & ((1 << CBITS) - 1)], 1);   // LDS atomic
        csr[p] = sd.x;
    }
}

// ---------------- mean aggregation (bf16 gather, f32 accumulate) ----------------
// 16 nodes/block (12500 waves: R8 lesson - gather is latency-bound, needs max TLP).
// x8 unroll: 32 streams in flight per wave.

__global__ __launch_bounds__(256) void aggregate_kernel(
    const unsigned short* __restrict__ xin,   // row stride 256 (pre-offset +128)
    const int* __restrict__ offsets, const int* __restrict__ csr,
    unsigned short* __restrict__ out,         // row stride 256 (offset 0)
    int nnodes) {
    int node = blockIdx.x * 16 + (threadIdx.x >> 4);
    int l16 = threadIdx.x & 15;
    if (node >= nnodes) return;
    int lo = offsets[node], hi = offsets[node + 1];
    float acc[8] = {0.f, 0.f, 0.f, 0.f, 0.f, 0.f, 0.f, 0.f};
    int k = lo;
    for (; k + 8 <= hi; k += 8) {
        int s[8];
        short8 v[8];
#pragma unroll
        for (int u = 0; u < 8; ++u) s[u] = csr[k + u];
#pragma unroll
        for (int u = 0; u < 8; ++u)
            v[u] = *reinterpret_cast<const short8*>(xin + (size_t)s[u] * 256 + l16 * 8);
#pragma unroll
        for (int u = 0; u < 8; ++u)
#pragma unroll
            for (int i = 0; i < 8; ++i) acc[i] += b2f((unsigned short)v[u][i]);
    }
    for (; k < hi; ++k) {
        int s = csr[k];
        const short8 v = *reinterpret_cast<const short8*>(xin + (size_t)s * 256 + l16 * 8);
#pragma unroll
        for (int i = 0; i < 8; ++i) acc[i] += b2f((unsigned short)v[i]);
    }
    float inv = 1.0f / fmaxf((float)(hi - lo), 1.0f);
    short8 r;
#pragma unroll
    for (int i = 0; i < 8; ++i) r[i] = (short)f2b(acc[i] * inv);
    *reinterpret_cast<short8*>(out + (size_t)node * 256 + l16 * 8) = r;
}

// ---------------- fused SAGE linear via MFMA (+ optional head epilogue) ----------------
// out[n][:] = l2norm(Acat[n][0..255] @ Wcat + b); RELU for layer 1;
// HEAD: logits = h @ Wfc + bfc -> softmax -> outf (no h2 table round-trip).

template <bool RELU, bool HEAD>
__global__ __launch_bounds__(256) void sage_mfma_kernel(
    const unsigned short* __restrict__ Acat, const unsigned short* __restrict__ WT,
    const float* __restrict__ bias, unsigned short* __restrict__ hout, int out_stride,
    const float* __restrict__ Wfc, const float* __restrict__ bfc,
    float* __restrict__ outf, int nnodes) {

    const int tid = threadIdx.x;
    const int w = tid >> 6, l = tid & 63;
    const int r16 = l & 15, g = l >> 4;
    const int rowbase = blockIdx.x * 64 + w * 16;

    f32x4 acc[8];
#pragma unroll
    for (int j = 0; j < 8; ++j) {
        float bj = bias[j * 16 + r16];
        acc[j] = (f32x4){bj, bj, bj, bj};
    }

    const unsigned short* ap = Acat + (size_t)(rowbase + r16) * 256 + g * 8;
    const unsigned short* bp = WT + (size_t)r16 * 256 + g * 8;

#pragma unroll
    for (int ks = 0; ks < 8; ++ks) {
        const short8 a = *reinterpret_cast<const short8*>(ap + ks * 32);
#pragma unroll
        for (int j = 0; j < 8; ++j) {
            const short8 b = *reinterpret_cast<const short8*>(bp + j * 4096 + ks * 32);
            acc[j] = __builtin_amdgcn_mfma_f32_16x16x32_bf16(a, b, acc[j], 0, 0, 0);
        }
    }

    float ss[4] = {0.f, 0.f, 0.f, 0.f};
#pragma unroll
    for (int j = 0; j < 8; ++j)
#pragma unroll
        for (int i = 0; i < 4; ++i) ss[i] += acc[j][i] * acc[j][i];
#pragma unroll
    for (int m = 1; m < 16; m <<= 1)
#pragma unroll
        for (int i = 0; i < 4; ++i) ss[i] += __shfl_xor(ss[i], m, 64);

    if (!HEAD) {
#pragma unroll
        for (int i = 0; i < 4; ++i) {
            int row = rowbase + g * 4 + i;
            if (row >= nnodes) continue;
            float sc = 1.0f / fmaxf(sqrtf(ss[i]), 1e-12f);
#pragma unroll
            for (int j = 0; j < 8; ++j) {
                float v = acc[j][i] * sc;
                if (RELU) v = fmaxf(v, 0.f);
                hout[(size_t)row * out_stride + j * 16 + r16] = f2b(v);
            }
        }
    } else {
        float w0[8], w1[8];
#pragma unroll
        for (int j = 0; j < 8; ++j) {
            const float2 wv = *reinterpret_cast<const float2*>(Wfc + (j * 16 + r16) * 2);
            w0[j] = wv.x; w1[j] = wv.y;
        }
        const float b0 = bfc[0], b1 = bfc[1];
#pragma unroll
        for (int i = 0; i < 4; ++i) {
            float sc = 1.0f / fmaxf(sqrtf(ss[i]), 1e-12f);
            float l0 = 0.f, l1 = 0.f;
#pragma unroll
            for (int j = 0; j < 8; ++j) {
                float v = acc[j][i] * sc;
                l0 = fmaf(v, w0[j], l0);
                l1 = fmaf(v, w1[j], l1);
            }
#pragma unroll
            for (int m = 1; m < 16; m <<= 1) {
                l0 += __shfl_xor(l0, m, 64);
                l1 += __shfl_xor(l1, m, 64);
            }
            int row = rowbase + g * 4 + i;
            if (r16 == 0 && row < nnodes) {
                float d0 = l0 + b0, d1 = l1 + b1;
                float mx = fmaxf(d0, d1);
                float e0 = expf(d0 - mx), e1 = expf(d1 - mx);
                float inv = 1.0f / (e0 + e1);
                outf[(size_t)row * 2]     = e0 * inv;
                outf[(size_t)row * 2 + 1] = e1 * inv;
            }
        }
    }
}

// ---------------- launch ----------------

extern "C" void kernel_launch(void* const* d_in, const int* in_sizes, int n_in,
                              void* d_out, int out_size, void* d_ws, size_t ws_size,
                              hipStream_t stream) {
    const float* x   = (const float*)d_in[0];
    const int*   ei  = (const int*)d_in[1];
    const float* W1l = (const float*)d_in[2];
    const float* b1l = (const float*)d_in[3];
    const float* W1r = (const float*)d_in[4];
    const float* W2l = (const float*)d_in[5];
    const float* b2l = (const float*)d_in[6];
    const float* W2r = (const float*)d_in[7];
    const float* Wfc = (const float*)d_in[8];
    const float* bfc = (const float*)d_in[9];

    const int N = in_sizes[0] / D;
    const int E = in_sizes[1] / 2;
    const int* src = ei;        // edge_index[0]
    const int* dst = ei + E;    // edge_index[1]
    const int NBC = (N + (1 << CBITS) - 1) >> CBITS;     // coarse buckets (196), <=256

    // workspace: bf16 feature tables first (16B aligned), ints after
    unsigned short* Acat1 = (unsigned short*)d_ws;        // N x 256 : [agg1 | xb]
    unsigned short* Acat2 = Acat1 + (size_t)N * 256;      // N x 256 : [agg2 | h1]
    int2* staging         = (int2*)Acat2;                 // E x int2 (dead until mfma1; build consumes before)
    unsigned short* WT1   = Acat2 + (size_t)N * 256;      // 128 x 256
    unsigned short* WT2   = WT1 + 128 * 256;              // 128 x 256
    int* bucketCnt  = (int*)(WT2 + 128 * 256);            // 256 } zeroed together (512 ints)
    int* cursorA    = bucketCnt + 256;                    // 256 }
    int* bucketBase = cursorA + 256;                      // NBC+1, padded to 260
    int* offsets    = bucketBase + 260;                   // N+1
    int* csr        = offsets + N + 1;                    // E

    const int nCast = (N * 16 + 255) / 256;

    // prep: cast x into Acat1[:,128:], transpose weights, zero counters (one launch)
    prep_kernel<<<nCast + 256 + 1, 256, 0, stream>>>(
        x, Acat1, nCast, N * 16, W1l, W1r, W2l, W2r, WT1, WT2, (int4*)bucketCnt);

    // CSR build: zero per-edge global atomics
    bucket_count_kernel<<<(E + 4095) / 4096, 256, 0, stream>>>(dst, bucketCnt, E);
    bucket_scan_kernel<<<1, 256, 0, stream>>>(bucketCnt, NBC, bucketBase, offsets, N, E);
    bin_coarse_kernel<<<(E + 4095) / 4096, 256, 0, stream>>>(src, dst, bucketBase, cursorA, staging, NBC, E);
    bucket_build_kernel<<<NBC, 256, 0, stream>>>(staging, bucketBase, offsets, csr, N);

    // layer 1: agg(xb) -> Acat1[:,0:128]; h1 = relu(l2norm(...)) -> Acat2[:,128:256]
    aggregate_kernel<<<(N + 15) / 16, 256, 0, stream>>>(Acat1 + 128, offsets, csr, Acat1, N);
    sage_mfma_kernel<true, false><<<(N + 63) / 64, 256, 0, stream>>>(
        Acat1, WT1, b1l, Acat2 + 128, 256, nullptr, nullptr, nullptr, N);

    // layer 2: agg(h1) -> Acat2[:,0:128]; head fused: softmax(l2norm(...)@Wfc+bfc) -> d_out
    aggregate_kernel<<<(N + 15) / 16, 256, 0, stream>>>(Acat2 + 128, offsets, csr, Acat2, N);
    sage_mfma_kernel<false, true><<<(N + 63) / 64, 256, 0, stream>>>(
        Acat2, WT2, b2l, nullptr, 0, Wfc, bfc, (float*)d_out, N);
}

// Round 10
// 133.270 us; speedup vs baseline: 3.2665x; 1.3631x over previous
//
#include <hip/hip_runtime.h>

#define D 128
#define CBITS 8    // 256 nodes per coarse bucket; NBC<=256 for N<=65536

typedef __attribute__((ext_vector_type(8))) short short8;
typedef __attribute__((ext_vector_type(4))) float f32x4;

__device__ __forceinline__ unsigned short f2b(float f) {
    unsigned u = __builtin_bit_cast(unsigned, f);
    u += 0x7fffu + ((u >> 16) & 1u);           // round-to-nearest-even
    return (unsigned short)(u >> 16);
}
__device__ __forceinline__ float b2f(unsigned short b) {
    unsigned u = ((unsigned)b) << 16;
    return __builtin_bit_cast(float, u);
}

// ---------------- combined prep: cast x -> Acat1[:,128:], W->WT bf16, zero counters --------

__global__ __launch_bounds__(256) void prep_kernel(
    const float* __restrict__ x, unsigned short* __restrict__ acat, int nCast, int n8,
    const float* __restrict__ W1l, const float* __restrict__ W1r,
    const float* __restrict__ W2l, const float* __restrict__ W2r,
    unsigned short* __restrict__ WT1, unsigned short* __restrict__ WT2,
    int4* __restrict__ zeroPtr, int* __restrict__ offsets, int nnodes, int E) {
    const int b = blockIdx.x;
    if (b < nCast) {
        int g = b * 256 + threadIdx.x;
        if (g < n8) {
            int row = g >> 4, chunk = g & 15;
            const float4 v0 = *reinterpret_cast<const float4*>(x + (size_t)g * 8);
            const float4 v1 = *reinterpret_cast<const float4*>(x + (size_t)g * 8 + 4);
            short8 r;
            r[0] = (short)f2b(v0.x); r[1] = (short)f2b(v0.y); r[2] = (short)f2b(v0.z); r[3] = (short)f2b(v0.w);
            r[4] = (short)f2b(v1.x); r[5] = (short)f2b(v1.y); r[6] = (short)f2b(v1.z); r[7] = (short)f2b(v1.w);
            *reinterpret_cast<short8*>(acat + (size_t)row * 256 + 128 + chunk * 8) = r;
        }
    } else if (b < nCast + 256) {
        int bb = b - nCast;
        int layer = bb >> 7;
        int j = bb & 127;
        int k = threadIdx.x;  // 0..255
        const float* Wl = layer ? W2l : W1l;
        const float* Wr = layer ? W2r : W1r;
        unsigned short* WT = layer ? WT2 : WT1;
        float v = (k < 128) ? Wl[k * D + j] : Wr[(k - 128) * D + j];
        WT[(size_t)j * 256 + k] = f2b(v);
    } else {
        if (threadIdx.x < 128) zeroPtr[threadIdx.x] = make_int4(0, 0, 0, 0);
        if (threadIdx.x == 0) offsets[nnodes] = E;
    }
}

// ---------------- CSR build: zero per-edge global atomics ----------------

__global__ __launch_bounds__(256) void bucket_count_kernel(
    const int* __restrict__ dst, int* __restrict__ bucketCnt, int E) {
    __shared__ int hist[256];
    const int t = threadIdx.x;
    hist[t] = 0;
    __syncthreads();
    const int base = blockIdx.x * 4096;
#pragma unroll
    for (int i = 0; i < 16; ++i) {
        int e = base + i * 256 + t;
        if (e < E) atomicAdd(&hist[dst[e] >> CBITS], 1);
    }
    __syncthreads();
    if (hist[t]) atomicAdd(&bucketCnt[t], hist[t]);
}

// bin_coarse: inline 256-wide scan of bucketCnt (removes bucket_scan launch),
// LDS-privatized reservation (R4 lesson: never 1 global atomic/edge).
__global__ __launch_bounds__(256) void bin_coarse_kernel(
    const int* __restrict__ src, const int* __restrict__ dst,
    const int* __restrict__ bucketCnt, int* __restrict__ cursorA,
    int2* __restrict__ staging, int E) {

    __shared__ int hist[256];
    __shared__ int lcur[256];
    const int t = threadIdx.x;

    // inclusive scan of bucketCnt in lcur -> myBase (exclusive)
    int cnt = bucketCnt[t];
    lcur[t] = cnt;
    __syncthreads();
    for (int d = 1; d < 256; d <<= 1) {
        int u = (t >= d) ? lcur[t - d] : 0;
        __syncthreads();
        lcur[t] += u;
        __syncthreads();
    }
    const int myBase = lcur[t] - cnt;
    __syncthreads();

    hist[t] = 0;
    __syncthreads();

    const int base = blockIdx.x * 4096;
    int sreg[16], dreg[16];
#pragma unroll
    for (int i = 0; i < 16; ++i) {
        int e = base + i * 256 + t;
        int s = 0, d = -1;
        if (e < E) {
            s = src[e]; d = dst[e];
            atomicAdd(&hist[d >> CBITS], 1);
        }
        sreg[i] = s; dreg[i] = d;
    }
    __syncthreads();
    {
        int h = hist[t];
        lcur[t] = myBase + (h ? atomicAdd(&cursorA[t], h) : 0);
    }
    __syncthreads();
#pragma unroll
    for (int i = 0; i < 16; ++i) {
        if (dreg[i] >= 0) {
            int p = atomicAdd(&lcur[dreg[i] >> CBITS], 1);   // LDS atomic
            staging[p] = make_int2(sreg[i], dreg[i]);
        }
    }
}

// bucket_build: one block per bucket; re-derives bucket bases via inline scan,
// then per-node hist + scan + ordered scatter, all in LDS.
__global__ __launch_bounds__(256) void bucket_build_kernel(
    const int2* __restrict__ staging, const int* __restrict__ bucketCnt,
    int* __restrict__ offsets, int* __restrict__ csr, int nnodes) {

    __shared__ int A1[256];
    __shared__ int A2[256];
    const int t = threadIdx.x;
    const int b = blockIdx.x;

    // inclusive scan of bucketCnt
    int cnt = bucketCnt[t];
    A1[t] = cnt;
    __syncthreads();
    for (int d = 1; d < 256; d <<= 1) {
        int u = (t >= d) ? A1[t - d] : 0;
        __syncthreads();
        A1[t] += u;
        __syncthreads();
    }
    const int end  = A1[b];
    const int base = end - bucketCnt[b];
    __syncthreads();

    // per-node histogram within bucket
    A1[t] = 0;
    __syncthreads();
    for (int i = base + t; i < end; i += 256)
        atomicAdd(&A1[staging[i].y & ((1 << CBITS) - 1)], 1);
    __syncthreads();
    A2[t] = A1[t];
    __syncthreads();
    for (int d = 1; d < 256; d <<= 1) {
        int u = (t >= d) ? A2[t - d] : 0;
        __syncthreads();
        A2[t] += u;
        __syncthreads();
    }
    const int excl = A2[t] - A1[t];
    const int node = (b << CBITS) + t;
    if (node < nnodes) offsets[node] = base + excl;
    __syncthreads();
    A1[t] = base + excl;          // reuse A1 as cursor
    __syncthreads();
    for (int i = base + t; i < end; i += 256) {
        int2 sd = staging[i];
        int p = atomicAdd(&A1[sd.y & ((1 << CBITS) - 1)], 1);   // LDS atomic
        csr[p] = sd.x;
    }
}

// ---------------- mean aggregation (bf16 gather, f32 accumulate) ----------------
// 16 nodes/block (max TLP - R8 lesson); x8 unroll = 32 streams in flight/wave.

__global__ __launch_bounds__(256) void aggregate_kernel(
    const unsigned short* __restrict__ xin,   // row stride 256 (pre-offset +128)
    const int* __restrict__ offsets, const int* __restrict__ csr,
    unsigned short* __restrict__ out,         // row stride 256 (offset 0)
    int nnodes) {
    int node = blockIdx.x * 16 + (threadIdx.x >> 4);
    int l16 = threadIdx.x & 15;
    if (node >= nnodes) return;
    int lo = offsets[node], hi = offsets[node + 1];
    float acc[8] = {0.f, 0.f, 0.f, 0.f, 0.f, 0.f, 0.f, 0.f};
    int k = lo;
    for (; k + 8 <= hi; k += 8) {
        int s[8];
        short8 v[8];
#pragma unroll
        for (int u = 0; u < 8; ++u) s[u] = csr[k + u];
#pragma unroll
        for (int u = 0; u < 8; ++u)
            v[u] = *reinterpret_cast<const short8*>(xin + (size_t)s[u] * 256 + l16 * 8);
#pragma unroll
        for (int u = 0; u < 8; ++u)
#pragma unroll
            for (int i = 0; i < 8; ++i) acc[i] += b2f((unsigned short)v[u][i]);
    }
    for (; k < hi; ++k) {
        int s = csr[k];
        const short8 v = *reinterpret_cast<const short8*>(xin + (size_t)s * 256 + l16 * 8);
#pragma unroll
        for (int i = 0; i < 8; ++i) acc[i] += b2f((unsigned short)v[i]);
    }
    float inv = 1.0f / fmaxf((float)(hi - lo), 1.0f);
    short8 r;
#pragma unroll
    for (int i = 0; i < 8; ++i) r[i] = (short)f2b(acc[i] * inv);
    *reinterpret_cast<short8*>(out + (size_t)node * 256 + l16 * 8) = r;
}

// ---------------- fused SAGE linear via MFMA (+ optional head epilogue) ----------------
// WT staged in 64KB swizzled LDS (kills the 200MB per-wave B re-read, R9 analysis);
// 32 rows/wave (acc[2][8]) reuses each B frag twice. 2 blocks/CU (LDS-limited).

template <bool RELU, bool HEAD>
__global__ __launch_bounds__(256) void sage_mfma_kernel(
    const unsigned short* __restrict__ Acat, const unsigned short* __restrict__ WT,
    const float* __restrict__ bias, unsigned short* __restrict__ hout, int out_stride,
    const float* __restrict__ Wfc, const float* __restrict__ bfc,
    float* __restrict__ outf, int nnodes) {

    __shared__ unsigned short Blds[128 * 256];   // 64KB, 16B-unit swizzle: c ^= row&7
    const int tid = threadIdx.x;

    {   // stage WT -> LDS (coalesced global, swizzled LDS)
        const short8* wsrc = reinterpret_cast<const short8*>(WT);
#pragma unroll
        for (int it = 0; it < 16; ++it) {
            int u = it * 256 + tid;                // 16B unit: 4096 total
            int row = u >> 5, c = u & 31;
            int cs = c ^ (row & 7);
            *reinterpret_cast<short8*>(
                reinterpret_cast<char*>(Blds) + row * 512 + cs * 16) = wsrc[u];
        }
    }
    __syncthreads();

    const int w = tid >> 6, l = tid & 63;
    const int r16 = l & 15, g = l >> 4;
    const int rowbase = blockIdx.x * 128 + w * 32;

    f32x4 acc[2][8];
#pragma unroll
    for (int j = 0; j < 8; ++j) {
        float bj = bias[j * 16 + r16];
        acc[0][j] = (f32x4){bj, bj, bj, bj};
        acc[1][j] = (f32x4){bj, bj, bj, bj};
    }

    const unsigned short* ap0 = Acat + (size_t)(rowbase + r16) * 256 + g * 8;
    const unsigned short* ap1 = ap0 + 16 * 256;

#pragma unroll
    for (int ks = 0; ks < 8; ++ks) {
        const short8 a0 = *reinterpret_cast<const short8*>(ap0 + ks * 32);
        const short8 a1 = *reinterpret_cast<const short8*>(ap1 + ks * 32);
        const int cs = ((ks * 4 + g) ^ (r16 & 7)) * 16;
#pragma unroll
        for (int j = 0; j < 8; ++j) {
            const short8 b = *reinterpret_cast<const short8*>(
                reinterpret_cast<const char*>(Blds) + (j * 16 + r16) * 512 + cs);
            acc[0][j] = __builtin_amdgcn_mfma_f32_16x16x32_bf16(a0, b, acc[0][j], 0, 0, 0);
            acc[1][j] = __builtin_amdgcn_mfma_f32_16x16x32_bf16(a1, b, acc[1][j], 0, 0, 0);
        }
    }

#pragma unroll
    for (int rb = 0; rb < 2; ++rb) {
        float ss[4] = {0.f, 0.f, 0.f, 0.f};
#pragma unroll
        for (int j = 0; j < 8; ++j)
#pragma unroll
            for (int i = 0; i < 4; ++i) ss[i] += acc[rb][j][i] * acc[rb][j][i];
#pragma unroll
        for (int m = 1; m < 16; m <<= 1)
#pragma unroll
            for (int i = 0; i < 4; ++i) ss[i] += __shfl_xor(ss[i], m, 64);

        if (!HEAD) {
#pragma unroll
            for (int i = 0; i < 4; ++i) {
                int row = rowbase + rb * 16 + g * 4 + i;
                if (row >= nnodes) continue;
                float sc = 1.0f / fmaxf(sqrtf(ss[i]), 1e-12f);
#pragma unroll
                for (int j = 0; j < 8; ++j) {
                    float v = acc[rb][j][i] * sc;
                    if (RELU) v = fmaxf(v, 0.f);
                    hout[(size_t)row * out_stride + j * 16 + r16] = f2b(v);
                }
            }
        } else {
            float w0[8], w1[8];
#pragma unroll
            for (int j = 0; j < 8; ++j) {
                const float2 wv = *reinterpret_cast<const float2*>(Wfc + (j * 16 + r16) * 2);
                w0[j] = wv.x; w1[j] = wv.y;
            }
            const float b0 = bfc[0], b1 = bfc[1];
#pragma unroll
            for (int i = 0; i < 4; ++i) {
                float sc = 1.0f / fmaxf(sqrtf(ss[i]), 1e-12f);
                float l0 = 0.f, l1 = 0.f;
#pragma unroll
                for (int j = 0; j < 8; ++j) {
                    float v = acc[rb][j][i] * sc;
                    l0 = fmaf(v, w0[j], l0);
                    l1 = fmaf(v, w1[j], l1);
                }
#pragma unroll
                for (int m = 1; m < 16; m <<= 1) {
                    l0 += __shfl_xor(l0, m, 64);
                    l1 += __shfl_xor(l1, m, 64);
                }
                int row = rowbase + rb * 16 + g * 4 + i;
                if (r16 == 0 && row < nnodes) {
                    float d0 = l0 + b0, d1 = l1 + b1;
                    float mx = fmaxf(d0, d1);
                    float e0 = expf(d0 - mx), e1 = expf(d1 - mx);
                    float inv = 1.0f / (e0 + e1);
                    outf[(size_t)row * 2]     = e0 * inv;
                    outf[(size_t)row * 2 + 1] = e1 * inv;
                }
            }
        }
    }
}

// ---------------- launch ----------------

extern "C" void kernel_launch(void* const* d_in, const int* in_sizes, int n_in,
                              void* d_out, int out_size, void* d_ws, size_t ws_size,
                              hipStream_t stream) {
    const float* x   = (const float*)d_in[0];
    const int*   ei  = (const int*)d_in[1];
    const float* W1l = (const float*)d_in[2];
    const float* b1l = (const float*)d_in[3];
    const float* W1r = (const float*)d_in[4];
    const float* W2l = (const float*)d_in[5];
    const float* b2l = (const float*)d_in[6];
    const float* W2r = (const float*)d_in[7];
    const float* Wfc = (const float*)d_in[8];
    const float* bfc = (const float*)d_in[9];

    const int N = in_sizes[0] / D;
    const int E = in_sizes[1] / 2;
    const int* src = ei;        // edge_index[0]
    const int* dst = ei + E;    // edge_index[1]
    const int NBC = (N + (1 << CBITS) - 1) >> CBITS;     // coarse buckets (196), <=256

    // workspace: bf16 feature tables first (16B aligned), ints after
    unsigned short* Acat1 = (unsigned short*)d_ws;        // N x 256 : [agg1 | xb]
    unsigned short* Acat2 = Acat1 + (size_t)N * 256;      // N x 256 : [agg2 | h1]
    int2* staging         = (int2*)Acat2;                 // E x int2 (dead until mfma1; consumed before)
    unsigned short* WT1   = Acat2 + (size_t)N * 256;      // 128 x 256
    unsigned short* WT2   = WT1 + 128 * 256;              // 128 x 256
    int* bucketCnt  = (int*)(WT2 + 128 * 256);            // 256 } zeroed together (512 ints)
    int* cursorA    = bucketCnt + 256;                    // 256 }
    int* offsets    = cursorA + 256;                      // N+1
    int* csr        = offsets + N + 1;                    // E

    const int nCast = (N * 16 + 255) / 256;

    // prep: cast x into Acat1[:,128:], transpose weights, zero counters, offsets[N]=E
    prep_kernel<<<nCast + 256 + 1, 256, 0, stream>>>(
        x, Acat1, nCast, N * 16, W1l, W1r, W2l, W2r, WT1, WT2,
        (int4*)bucketCnt, offsets, N, E);

    // CSR build: zero per-edge global atomics, scans inlined
    bucket_count_kernel<<<(E + 4095) / 4096, 256, 0, stream>>>(dst, bucketCnt, E);
    bin_coarse_kernel<<<(E + 4095) / 4096, 256, 0, stream>>>(src, dst, bucketCnt, cursorA, staging, E);
    bucket_build_kernel<<<NBC, 256, 0, stream>>>(staging, bucketCnt, offsets, csr, N);

    // layer 1: agg(xb) -> Acat1[:,0:128]; h1 = relu(l2norm(...)) -> Acat2[:,128:256]
    aggregate_kernel<<<(N + 15) / 16, 256, 0, stream>>>(Acat1 + 128, offsets, csr, Acat1, N);
    sage_mfma_kernel<true, false><<<(N + 127) / 128, 256, 0, stream>>>(
        Acat1, WT1, b1l, Acat2 + 128, 256, nullptr, nullptr, nullptr, N);

    // layer 2: agg(h1) -> Acat2[:,0:128]; head fused: softmax(l2norm(...)@Wfc+bfc) -> d_out
    aggregate_kernel<<<(N + 15) / 16, 256, 0, stream>>>(Acat2 + 128, offsets, csr, Acat2, N);
    sage_mfma_kernel<false, true><<<(N + 127) / 128, 256, 0, stream>>>(
        Acat2, WT2, b2l, nullptr, 0, Wfc, bfc, (float*)d_out, N);
}